// Round 6
// baseline (758.890 us; speedup 1.0000x reference)
//
#include <hip/hip_runtime.h>
#include <math.h>

#define B_ 2
#define P_ 16384
#define C_ 5
#define S_ 4096
#define KNN_ 8
#define L_ 64

typedef unsigned short u16;
typedef unsigned int u32;

// ---- static scratch: fully rewritten every call before any read ----
__device__ int   g_f32x, g_f32w;               // dtype flags (1 = float32)
__device__ float g_mnmx[16];
__device__ int   g_idx0[B_ * S_];
__device__ int   g_idxk[B_ * KNN_ * S_];
__device__ float g_partials[256 * 128];
__device__ float g_stats[128];

__device__ __forceinline__ float bf2f(u16 u) {
  union { u32 i; float f; } c; c.i = ((u32)u) << 16; return c.f;
}
__device__ __forceinline__ u16 f2bf(float f) {
  union { float f; u32 i; } c; c.f = f;
  u32 r = c.i + 0x7fffu + ((c.i >> 16) & 1u);
  return (u16)(r >> 16);
}
// dtype-agnostic scalar load
__device__ __forceinline__ float ldany(const void* p, int i, int f32) {
  return f32 ? ((const float*)p)[i] : bf2f(((const u16*)p)[i]);
}

// ---------------- dtype detector ----------------
__device__ __forceinline__ int chk_bad(const void* p, int n, int tid) {
  int bad = 0;
  for (int i = tid; i < n; i += 256) {
    float f = bf2f(((const u16*)p)[i]);
    if (!(f == f) || fabsf(f) > 1024.0f) bad = 1;
  }
  return bad;
}
__global__ __launch_bounds__(256) void k_detect(const void* x, const void* wpos,
                                                const void* wconv, const void* wa1,
                                                const void* wa2, const void* wb1,
                                                const void* wb2) {
  __shared__ int sx, sw;
  int tid = threadIdx.x;
  if (tid == 0) { sx = 0; sw = 0; }
  __syncthreads();
  int bx = chk_bad(x, 1024, tid);
  int bw = chk_bad(wpos, 320, tid) | chk_bad(wconv, 128, tid) | chk_bad(wa1, 2048, tid)
         | chk_bad(wa2, 32, tid)   | chk_bad(wb1, 4096, tid)  | chk_bad(wb2, 256, tid);
  if (bx) atomicOr(&sx, 1);
  if (bw) atomicOr(&sw, 1);
  __syncthreads();
  if (tid == 0) { g_f32x = sx; g_f32w = sw; }
}

// ---------------- min/max over P for channels 0,1 ----------------
__global__ __launch_bounds__(256) void k_minmax(const void* __restrict__ x) {
  int f32 = g_f32x;
  int bc = blockIdx.x;            // 0..3 : b*2 + ch
  int b = bc >> 1, ch = bc & 1;
  int base = (b * C_ + ch) * P_;
  float mn = INFINITY, mx = -INFINITY;
  for (int p = threadIdx.x; p < P_; p += 256) {
    float v = ldany(x, base + p, f32);
    mn = fminf(mn, v); mx = fmaxf(mx, v);
  }
  for (int off = 32; off; off >>= 1) {
    mn = fminf(mn, __shfl_down(mn, off));
    mx = fmaxf(mx, __shfl_down(mx, off));
  }
  __shared__ float smn[4], smx[4];
  int wid = threadIdx.x >> 6;
  if ((threadIdx.x & 63) == 0) { smn[wid] = mn; smx[wid] = mx; }
  __syncthreads();
  if (threadIdx.x == 0) {
    for (int w = 1; w < 4; ++w) { mn = fminf(mn, smn[w]); mx = fmaxf(mx, smx[w]); }
    g_mnmx[bc * 2] = mn; g_mnmx[bc * 2 + 1] = mx;
  }
}

// ---------------- kNN #1 : nearest of 16384 2D points, 32 queries/block ----------------
// contraction-free f32, np association order; candidate (a0,a1,xx) staged in LDS
template<int F32>
__device__ __forceinline__ void knn1_impl(const void* __restrict__ xv) {
  __shared__ float4 s4[4096];               // (a0, a1, xx, 0) ; 64 KB
  int tid = threadIdx.x;
  int q = tid >> 3, j = tid & 7;
  int sg = blockIdx.x * 32 + q;             // global query id (b*4096+s)
  int b = sg >> 12, s = sg & (S_ - 1);
  float mn0 = g_mnmx[(b * 2 + 0) * 2], mx0 = g_mnmx[(b * 2 + 0) * 2 + 1];
  float mn1 = g_mnmx[(b * 2 + 1) * 2], mx1 = g_mnmx[(b * 2 + 1) * 2 + 1];
  float mm0 = (float)(s & (L_ - 1)) * 0.015625f;
  float mm1 = (float)(s >> 6) * 0.015625f;
  float ps0 = __fadd_rn(__fmul_rn(mm0, __fsub_rn(mx0, mn0)), mn0);
  float ps1 = __fadd_rn(__fmul_rn(mm1, __fsub_rn(mx1, mn1)), mn1);
  float xx2 = __fadd_rn(__fmul_rn(ps0, ps0), __fmul_rn(ps1, ps1));
  int base0 = b * C_ * P_, base1 = base0 + P_;
  float best = -INFINITY; int bestp = 0x7fffffff;
  for (int c = 0; c < 4; ++c) {
    __syncthreads();
    for (int i = tid; i < 4096; i += 256) {
      int gi = c * 4096 + i;
      float a0 = F32 ? ((const float*)xv)[base0 + gi] : bf2f(((const u16*)xv)[base0 + gi]);
      float a1 = F32 ? ((const float*)xv)[base1 + gi] : bf2f(((const u16*)xv)[base1 + gi]);
      float xx = __fadd_rn(__fmul_rn(a0, a0), __fmul_rn(a1, a1));
      s4[i] = make_float4(a0, a1, xx, 0.0f);
    }
    __syncthreads();
#pragma unroll 4
    for (int t = 0; t < 512; ++t) {
      float4 v = s4[t * 8 + j];             // lanes j=0..7: consecutive quads, queries broadcast
      float dot = __fadd_rn(__fmul_rn(v.x, ps0), __fmul_rn(v.y, ps1));
      float inner = __fmul_rn(-2.0f, dot);
      float d = __fsub_rn(__fsub_rn(-v.z, inner), xx2);
      if (d > best) { best = d; bestp = c * 4096 + t * 8 + j; }  // idx increasing in-thread
    }
  }
  // exact 8-lane merge (val desc, idx asc)
  for (int m = 1; m < 8; m <<= 1) {
    float ov = __shfl_xor(best, m, 8); int op = __shfl_xor(bestp, m, 8);
    if (ov > best || (ov == best && op < bestp)) { best = ov; bestp = op; }
  }
  if (j == 0) g_idx0[sg] = bestp;
}
__global__ __launch_bounds__(256) void k_knn1(const void* __restrict__ x) {
  if (g_f32x) knn1_impl<1>(x); else knn1_impl<0>(x);
}

// ---------------- kNN #2 : top-8 of 16384 3D points, 32 queries/block ----------------
template<int F32>
__device__ __forceinline__ void knn2_impl(const void* __restrict__ xv) {
  __shared__ float4 s4[4096];               // (a0, a1, a2, xx) ; 64 KB
  int tid = threadIdx.x;
  int q = tid >> 3, j = tid & 7;
  int sg = blockIdx.x * 32 + q;
  int b = sg >> 12, s = sg & (S_ - 1);
  int base0 = b * C_ * P_, base1 = base0 + P_, base2 = base1 + P_;
  int qi = g_idx0[sg] & (P_ - 1);
  float q0 = F32 ? ((const float*)xv)[base0 + qi] : bf2f(((const u16*)xv)[base0 + qi]);
  float q1 = F32 ? ((const float*)xv)[base1 + qi] : bf2f(((const u16*)xv)[base1 + qi]);
  float q2 = F32 ? ((const float*)xv)[base2 + qi] : bf2f(((const u16*)xv)[base2 + qi]);
  float xx2 = __fadd_rn(__fadd_rn(__fmul_rn(q0, q0), __fmul_rn(q1, q1)), __fmul_rn(q2, q2));
  float tv[8]; int ti[8];
#pragma unroll
  for (int k = 0; k < 8; ++k) { tv[k] = -INFINITY; ti[k] = 0x7fffffff; }
  for (int c = 0; c < 4; ++c) {
    __syncthreads();
    for (int i = tid; i < 4096; i += 256) {
      int gi = c * 4096 + i;
      float a0 = F32 ? ((const float*)xv)[base0 + gi] : bf2f(((const u16*)xv)[base0 + gi]);
      float a1 = F32 ? ((const float*)xv)[base1 + gi] : bf2f(((const u16*)xv)[base1 + gi]);
      float a2 = F32 ? ((const float*)xv)[base2 + gi] : bf2f(((const u16*)xv)[base2 + gi]);
      float xx = __fadd_rn(__fadd_rn(__fmul_rn(a0, a0), __fmul_rn(a1, a1)), __fmul_rn(a2, a2));
      s4[i] = make_float4(a0, a1, a2, xx);
    }
    __syncthreads();
#pragma unroll 4
    for (int t = 0; t < 512; ++t) {
      float4 v = s4[t * 8 + j];
      float dot = __fadd_rn(__fadd_rn(__fmul_rn(v.x, q0), __fmul_rn(v.y, q1)), __fmul_rn(v.z, q2));
      float inner = __fmul_rn(-2.0f, dot);
      float d = __fsub_rn(__fsub_rn(-v.w, inner), xx2);
      if (d > tv[7]) {                       // in-thread idx increasing: ties correctly lose
        float vv = d; int ix = c * 4096 + t * 8 + j;
#pragma unroll
        for (int k = 0; k < 8; ++k) {        // sorted insert (val desc, idx asc)
          bool sw = (vv > tv[k]) || (vv == tv[k] && ix < ti[k]);
          float ov = tv[k]; int oi = ti[k];
          tv[k] = sw ? vv : tv[k]; ti[k] = sw ? ix : ti[k];
          vv = sw ? ov : vv;      ix = sw ? oi : ix;
        }
      }
    }
  }
  // exact 8-round merge of the 8 lanes' sorted lists (val desc, idx asc)
  int head = 0;
  int mywin = 0;
#pragma unroll
  for (int r = 0; r < 8; ++r) {
    float v = (head < 8) ? tv[head] : -INFINITY;
    int ix = (head < 8) ? ti[head] : 0x7fffffff;
    for (int m = 1; m < 8; m <<= 1) {
      float ov = __shfl_xor(v, m, 8); int op = __shfl_xor(ix, m, 8);
      if (ov > v || (ov == v && op < ix)) { v = ov; ix = op; }
    }
    if (j == r) mywin = ix;                  // lane r keeps rank r
    if (head < 8 && ti[head] == ix) head++;  // candidate idx unique per thread
  }
  g_idxk[b * 32768 + j * 4096 + s] = mywin;  // rank-major (B,k,s) like ref
}
__global__ __launch_bounds__(256) void k_knn2(const void* __restrict__ x) {
  if (g_f32x) knn2_impl<1>(x); else knn2_impl<0>(x);
}

// ---------------- helper: gather + the two matvecs for one element ----------------
__device__ __forceinline__ void elem_vals(const void* xv, int xf32, int xbase,
                                          const int* fb, int n,
                                          const float* sWpos, const float* sbpos,
                                          const float* sWconv, const float* sbconv,
                                          float* val /*[64]*/) {
  int p = fb[n] & (P_ - 1);
  int p0 = fb[n & ~7] & (P_ - 1);           // j=0 slot of same group
  float xvv[4];
#pragma unroll
  for (int c = 0; c < 4; ++c) xvv[c] = ldany(xv, xbase + c * P_ + p, xf32);
  float pc[3];
#pragma unroll
  for (int c = 0; c < 3; ++c) pc[c] = ldany(xv, xbase + c * P_ + p0, xf32);
  float d0 = xvv[0] - pc[0], d1 = xvv[1] - pc[1], d2 = xvv[2] - pc[2];
  float sq = d0 * d0 + d1 * d1 + d2 * d2;
  float temp = (sq > 0.0f) ? sqrtf(sq) : 0.0f;
  float pe[10] = {xvv[0], xvv[1], xvv[2], pc[0], pc[1], pc[2], d0, d1, d2, temp};
#pragma unroll
  for (int o = 0; o < 32; ++o) {            // val[0..31] = conv branch
    float acc = sbconv[o];
#pragma unroll
    for (int c = 0; c < 4; ++c) acc = fmaf(sWconv[o * 4 + c], xvv[c], acc);
    val[o] = acc;
  }
#pragma unroll
  for (int o = 0; o < 32; ++o) {            // val[32..63] = pos branch
    float acc = sbpos[o];
#pragma unroll
    for (int c = 0; c < 10; ++c) acc = fmaf(sWpos[o * 10 + c], pe[c], acc);
    val[32 + o] = acc;
  }
}

// ---------------- BN partial sums ----------------
__global__ __launch_bounds__(256) void k_partial(const void* __restrict__ x,
                                                 const void* __restrict__ Wpos,
                                                 const void* __restrict__ bpos,
                                                 const void* __restrict__ Wconv,
                                                 const void* __restrict__ bconv) {
  __shared__ float sWpos[320], sbpos[32], sWconv[128], sbconv[32];
  __shared__ float sacc[4][128];
  int tid = threadIdx.x;
  int xf32 = g_f32x, wf32 = g_f32w;
  for (int i2 = tid; i2 < 320; i2 += 256) sWpos[i2] = ldany(Wpos, i2, wf32);
  if (tid < 128) sWconv[tid] = ldany(Wconv, tid, wf32);
  if (tid < 32) { sbpos[tid] = ldany(bpos, tid, wf32); sbconv[tid] = ldany(bconv, tid, wf32); }
  __syncthreads();
  int t = blockIdx.x * 256 + tid;          // < 65536
  int b = t >> 15, n = t & 32767;
  const int* fb = g_idxk + b * 32768;
  float val[64];
  elem_vals(x, xf32, b * C_ * P_, fb, n, sWpos, sbpos, sWconv, sbconv, val);
  int wid = tid >> 6, lane = tid & 63;
#pragma unroll
  for (int c = 0; c < 64; ++c) {
    float s = val[c], q = val[c] * val[c];
    for (int off = 32; off; off >>= 1) {
      s += __shfl_down(s, off);
      q += __shfl_down(q, off);
    }
    if (lane == 0) { sacc[wid][c * 2] = s; sacc[wid][c * 2 + 1] = q; }
  }
  __syncthreads();
  if (tid < 128) {
    g_partials[blockIdx.x * 128 + tid] =
        sacc[0][tid] + sacc[1][tid] + sacc[2][tid] + sacc[3][tid];
  }
}

// ---------------- finalize BN stats ----------------
__global__ void k_finalize(const void* __restrict__ g1, const void* __restrict__ be1,
                           const void* __restrict__ g2, const void* __restrict__ be2) {
  int ch = threadIdx.x;                    // blockDim = 64
  if (ch >= 64) return;
  int wf32 = g_f32w;
  float sum = 0.f, sq = 0.f;
  for (int blk = 0; blk < 256; ++blk) {
    sum += g_partials[blk * 128 + ch * 2];
    sq  += g_partials[blk * 128 + ch * 2 + 1];
  }
  float mean = sum * (1.0f / 65536.0f);
  float var = sq * (1.0f / 65536.0f) - mean * mean;
  int o = ch & 31;
  float g  = ldany(ch < 32 ? g1 : g2, o, wf32);
  float be = ldany(ch < 32 ? be1 : be2, o, wf32);
  float scale = g / sqrtf(var + 1e-5f);
  g_stats[ch * 2] = scale;
  g_stats[ch * 2 + 1] = be - mean * scale;
}

// ---------------- pass 2 : recompute + BN + attention + output ----------------
__global__ __launch_bounds__(256) void k_pass2(const void* __restrict__ x,
                                               const void* __restrict__ Wpos,
                                               const void* __restrict__ bpos,
                                               const void* __restrict__ Wconv,
                                               const void* __restrict__ bconv,
                                               const void* __restrict__ Wa1,
                                               const void* __restrict__ ba1,
                                               const void* __restrict__ Wa2,
                                               const void* __restrict__ ba2,
                                               const void* __restrict__ Wb1,
                                               const void* __restrict__ bb1,
                                               const void* __restrict__ Wb2,
                                               const void* __restrict__ bb2,
                                               void* __restrict__ out) {
  __shared__ float sWpos[320], sbpos[32], sWconv[128], sbconv[32];
  __shared__ float sWa1[2048], sba1[32], sWa2[32];
  __shared__ float sWb1[64 * 65];
  __shared__ float sbb1[64], sWb2[256], sbb2[64], sstats[128];
  __shared__ float sba2;
  int tid = threadIdx.x;
  int xf32 = g_f32x, wf32 = g_f32w;
  for (int i2 = tid; i2 < 320; i2 += 256) sWpos[i2] = ldany(Wpos, i2, wf32);
  if (tid < 128) sWconv[tid] = ldany(Wconv, tid, wf32);
  if (tid < 32) { sbpos[tid] = ldany(bpos, tid, wf32); sbconv[tid] = ldany(bconv, tid, wf32); }
  for (int i2 = tid; i2 < 2048; i2 += 256) sWa1[i2] = ldany(Wa1, i2, wf32);
  for (int i2 = tid; i2 < 4096; i2 += 256) sWb1[(i2 >> 6) * 65 + (i2 & 63)] = ldany(Wb1, i2, wf32);
  if (tid >= 32 && tid < 64) { sba1[tid - 32] = ldany(ba1, tid - 32, wf32); sWa2[tid - 32] = ldany(Wa2, tid - 32, wf32); }
  if (tid >= 64 && tid < 128) { sbb1[tid - 64] = ldany(bb1, tid - 64, wf32); sbb2[tid - 64] = ldany(bb2, tid - 64, wf32); }
  if (tid >= 128 && tid < 256) sstats[tid - 128] = g_stats[tid - 128];
  sWb2[tid] = ldany(Wb2, tid, wf32);
  if (tid == 0) sba2 = ldany(ba2, 0, wf32);
  __syncthreads();
  int g = blockIdx.x * 32 + (tid >> 3);     // group = (b,i)
  int j = tid & 7;
  int b = g >> 12, i = g & (S_ - 1);
  int n = i * 8 + j;
  const int* fb = g_idxk + b * 32768;
  int xbase = b * C_ * P_;
  float feat[64];
  elem_vals(x, xf32, xbase, fb, n, sWpos, sbpos, sWconv, sbconv, feat);
#pragma unroll
  for (int c = 0; c < 64; ++c) {
    float v = fmaf(feat[c], sstats[c * 2], sstats[c * 2 + 1]);
    feat[c] = (v >= 0.f) ? v : 0.2f * v;
  }
  float att = sba2;
  for (int h = 0; h < 32; ++h) {
    float acc = sba1[h];
#pragma unroll
    for (int c = 0; c < 64; ++c) acc = fmaf(sWa1[h * 64 + c], feat[c], acc);
    acc = (acc >= 0.f) ? acc : 0.2f * acc;
    att = fmaf(sWa2[h], acc, att);
  }
  float mxv = att;
  for (int mk = 1; mk < 8; mk <<= 1) mxv = fmaxf(mxv, __shfl_xor(mxv, mk, 8));
  float e = expf(att - mxv);
  float se = e;
  for (int mk = 1; mk < 8; mk <<= 1) se += __shfl_xor(se, mk, 8);
  float a = e / se;
#pragma unroll
  for (int c = 0; c < 64; ++c) {
    float w = feat[c] * a;
    w += __shfl_xor(w, 1, 8);
    w += __shfl_xor(w, 2, 8);
    w += __shfl_xor(w, 4, 8);
    feat[c] = w;
  }
  int p0 = fb[i * 8] & (P_ - 1);
  float xc0 = ldany(x, xbase + p0, xf32);
  float xc1 = ldany(x, xbase + P_ + p0, xf32);
  float xc2 = ldany(x, xbase + 2 * P_ + p0, xf32);
  float xc3 = ldany(x, xbase + 3 * P_ + p0, xf32);
  int obase = b * 69 * S_;
#pragma unroll
  for (int oc = 0; oc < 8; ++oc) {
    int o = j * 8 + oc;
    float acc = sbb1[o];
#pragma unroll
    for (int c = 0; c < 64; ++c) acc = fmaf(sWb1[o * 65 + c], feat[c], acc);
    float acc2 = sbb2[o];
    acc2 = fmaf(sWb2[o * 4 + 0], xc0, acc2);
    acc2 = fmaf(sWb2[o * 4 + 1], xc1, acc2);
    acc2 = fmaf(sWb2[o * 4 + 2], xc2, acc2);
    acc2 = fmaf(sWb2[o * 4 + 3], xc3, acc2);
    float r = acc + acc2;
    r = (r >= 0.f) ? r : 0.01f * r;
    int oi = obase + (5 + o) * S_ + i;
    if (xf32) ((float*)out)[oi] = r; else ((u16*)out)[oi] = f2bf(r);
  }
  if (j == 0) {                              // raw pass-through of x1[:, :5, :, 0]
#pragma unroll
    for (int c = 0; c < 5; ++c) {
      int oi = obase + c * S_ + i;
      if (xf32) ((float*)out)[oi] = ((const float*)x)[xbase + c * P_ + p0];
      else      ((u16*)out)[oi]   = ((const u16*)x)[xbase + c * P_ + p0];
    }
  }
}

extern "C" void kernel_launch(void* const* d_in, const int* in_sizes, int n_in,
                              void* d_out, int out_size, void* d_ws, size_t ws_size,
                              hipStream_t stream) {
  const void* x     = d_in[0];
  const void* Wpos  = d_in[1];
  const void* bpos  = d_in[2];
  const void* g2    = d_in[3];
  const void* be2   = d_in[4];
  const void* Wconv = d_in[5];
  const void* bconv = d_in[6];
  const void* g1    = d_in[7];
  const void* be1   = d_in[8];
  const void* Wa1   = d_in[9];
  const void* ba1   = d_in[10];
  const void* Wa2   = d_in[11];
  const void* ba2   = d_in[12];
  const void* Wb1   = d_in[13];
  const void* bb1   = d_in[14];
  const void* Wb2   = d_in[15];
  const void* bb2   = d_in[16];
  (void)d_ws; (void)ws_size; (void)in_sizes; (void)n_in;

  hipLaunchKernelGGL(k_detect, dim3(1), dim3(256), 0, stream,
                     x, Wpos, Wconv, Wa1, Wa2, Wb1, Wb2);
  hipLaunchKernelGGL(k_minmax, dim3(4), dim3(256), 0, stream, x);
  hipLaunchKernelGGL(k_knn1, dim3(256), dim3(256), 0, stream, x);
  hipLaunchKernelGGL(k_knn2, dim3(256), dim3(256), 0, stream, x);
  hipLaunchKernelGGL(k_partial, dim3(256), dim3(256), 0, stream, x,
                     Wpos, bpos, Wconv, bconv);
  hipLaunchKernelGGL(k_finalize, dim3(1), dim3(64), 0, stream,
                     g1, be1, g2, be2);
  hipLaunchKernelGGL(k_pass2, dim3(256), dim3(256), 0, stream, x,
                     Wpos, bpos, Wconv, bconv, Wa1, ba1, Wa2, ba2,
                     Wb1, bb1, Wb2, bb2, d_out);
}

// Round 7
// 625.294 us; speedup vs baseline: 1.2137x; 1.2137x over previous
//
#include <hip/hip_runtime.h>
#include <math.h>

#define B_ 2
#define P_ 16384
#define C_ 5
#define S_ 4096
#define KNN_ 8
#define L_ 64

typedef unsigned short u16;
typedef unsigned int u32;

// ---- static scratch: fully rewritten every call before any read ----
__device__ int   g_f32x, g_f32w;               // dtype flags (1 = float32)
__device__ float g_mnmx[16];
__device__ int   g_idx0[B_ * S_];
__device__ int   g_idxk[B_ * KNN_ * S_];
__device__ float g_partials[256 * 128];
__device__ float g_stats[128];

__device__ __forceinline__ float bf2f(u16 u) {
  union { u32 i; float f; } c; c.i = ((u32)u) << 16; return c.f;
}
__device__ __forceinline__ u16 f2bf(float f) {
  union { float f; u32 i; } c; c.f = f;
  u32 r = c.i + 0x7fffu + ((c.i >> 16) & 1u);
  return (u16)(r >> 16);
}
// dtype-agnostic scalar load
__device__ __forceinline__ float ldany(const void* p, int i, int f32) {
  return f32 ? ((const float*)p)[i] : bf2f(((const u16*)p)[i]);
}

// ---------------- dtype detector ----------------
__device__ __forceinline__ int chk_bad(const void* p, int n, int tid) {
  int bad = 0;
  for (int i = tid; i < n; i += 256) {
    float f = bf2f(((const u16*)p)[i]);
    if (!(f == f) || fabsf(f) > 1024.0f) bad = 1;
  }
  return bad;
}
__global__ __launch_bounds__(256) void k_detect(const void* x, const void* wpos,
                                                const void* wconv, const void* wa1,
                                                const void* wa2, const void* wb1,
                                                const void* wb2) {
  __shared__ int sx, sw;
  int tid = threadIdx.x;
  if (tid == 0) { sx = 0; sw = 0; }
  __syncthreads();
  int bx = chk_bad(x, 1024, tid);
  int bw = chk_bad(wpos, 320, tid) | chk_bad(wconv, 128, tid) | chk_bad(wa1, 2048, tid)
         | chk_bad(wa2, 32, tid)   | chk_bad(wb1, 4096, tid)  | chk_bad(wb2, 256, tid);
  if (bx) atomicOr(&sx, 1);
  if (bw) atomicOr(&sw, 1);
  __syncthreads();
  if (tid == 0) { g_f32x = sx; g_f32w = sw; }
}

// ---------------- min/max over P for channels 0,1 ----------------
__global__ __launch_bounds__(256) void k_minmax(const void* __restrict__ x) {
  int f32 = g_f32x;
  int bc = blockIdx.x;            // 0..3 : b*2 + ch
  int b = bc >> 1, ch = bc & 1;
  int base = (b * C_ + ch) * P_;
  float mn = INFINITY, mx = -INFINITY;
  for (int p = threadIdx.x; p < P_; p += 256) {
    float v = ldany(x, base + p, f32);
    mn = fminf(mn, v); mx = fmaxf(mx, v);
  }
  for (int off = 32; off; off >>= 1) {
    mn = fminf(mn, __shfl_down(mn, off));
    mx = fmaxf(mx, __shfl_down(mx, off));
  }
  __shared__ float smn[4], smx[4];
  int wid = threadIdx.x >> 6;
  if ((threadIdx.x & 63) == 0) { smn[wid] = mn; smx[wid] = mx; }
  __syncthreads();
  if (threadIdx.x == 0) {
    for (int w = 1; w < 4; ++w) { mn = fminf(mn, smn[w]); mx = fmaxf(mx, smx[w]); }
    g_mnmx[bc * 2] = mn; g_mnmx[bc * 2 + 1] = mx;
  }
}

// ---------------- kNN #1 : nearest of 16384 2D points ----------------
// 512 threads = 16 groups x 32 lanes; 2 queries per thread; LDS-staged candidates.
// contraction-free f32, np association order.
__global__ __launch_bounds__(512) void k_knn1(const void* __restrict__ xv) {
  __shared__ float4 s4[4096];               // (a0, a1, xx, 0) ; 64 KB
  const int f32 = g_f32x;
  int tid = threadIdx.x;
  int grp = tid >> 5, j = tid & 31;
  int sg0 = blockIdx.x * 32 + grp * 2;      // first of this thread's 2 queries
  int b = sg0 >> 12;
  float mn0 = g_mnmx[(b * 2 + 0) * 2], mx0 = g_mnmx[(b * 2 + 0) * 2 + 1];
  float mn1 = g_mnmx[(b * 2 + 1) * 2], mx1 = g_mnmx[(b * 2 + 1) * 2 + 1];
  int base0 = b * C_ * P_, base1 = base0 + P_;
  float ps0[2], ps1[2], xx2[2], best[2]; int bestp[2];
#pragma unroll
  for (int qq = 0; qq < 2; ++qq) {
    int s = (sg0 + qq) & (S_ - 1);
    float mm0 = (float)(s & (L_ - 1)) * 0.015625f;
    float mm1 = (float)(s >> 6) * 0.015625f;
    ps0[qq] = __fadd_rn(__fmul_rn(mm0, __fsub_rn(mx0, mn0)), mn0);
    ps1[qq] = __fadd_rn(__fmul_rn(mm1, __fsub_rn(mx1, mn1)), mn1);
    xx2[qq] = __fadd_rn(__fmul_rn(ps0[qq], ps0[qq]), __fmul_rn(ps1[qq], ps1[qq]));
    best[qq] = -INFINITY; bestp[qq] = 0x7fffffff;
  }
  for (int c = 0; c < 4; ++c) {
    __syncthreads();
    for (int i = tid; i < 4096; i += 512) {
      int gi = c * 4096 + i;
      float a0 = ldany(xv, base0 + gi, f32);
      float a1 = ldany(xv, base1 + gi, f32);
      float xx = __fadd_rn(__fmul_rn(a0, a0), __fmul_rn(a1, a1));
      s4[i] = make_float4(a0, a1, xx, 0.0f);
    }
    __syncthreads();
    for (int t = 0; t < 128; ++t) {
      float4 v = s4[t * 32 + j];
      int ix = c * 4096 + t * 32 + j;       // increasing in-thread
#pragma unroll
      for (int qq = 0; qq < 2; ++qq) {
        float dot = __fadd_rn(__fmul_rn(v.x, ps0[qq]), __fmul_rn(v.y, ps1[qq]));
        float inner = __fmul_rn(-2.0f, dot);
        float d = __fsub_rn(__fsub_rn(-v.z, inner), xx2[qq]);
        if (d > best[qq]) { best[qq] = d; bestp[qq] = ix; }
      }
    }
  }
#pragma unroll
  for (int qq = 0; qq < 2; ++qq) {
    float v = best[qq]; int ix = bestp[qq];
    for (int m = 1; m < 32; m <<= 1) {
      float ov = __shfl_xor(v, m, 32); int op = __shfl_xor(ix, m, 32);
      if (ov > v || (ov == v && op < ix)) { v = ov; ix = op; }
    }
    if (j == 0) g_idx0[sg0 + qq] = ix;
  }
}

// ---------------- kNN #2 : top-8 of 16384 3D points ----------------
// 512 threads = 16 groups x 32 lanes; 2 queries per thread.
__global__ __launch_bounds__(512) void k_knn2(const void* __restrict__ xv) {
  __shared__ float4 s4[4096];               // (a0, a1, a2, xx) ; 64 KB
  const int f32 = g_f32x;
  int tid = threadIdx.x;
  int grp = tid >> 5, j = tid & 31;
  int sg0 = blockIdx.x * 32 + grp * 2;
  int b = sg0 >> 12;
  int base0 = b * C_ * P_, base1 = base0 + P_, base2 = base1 + P_;
  float q0[2], q1[2], q2[2], xx2[2];
  float tv[2][8]; int ti[2][8];
#pragma unroll
  for (int qq = 0; qq < 2; ++qq) {
    int qi = g_idx0[sg0 + qq] & (P_ - 1);
    q0[qq] = ldany(xv, base0 + qi, f32);
    q1[qq] = ldany(xv, base1 + qi, f32);
    q2[qq] = ldany(xv, base2 + qi, f32);
    xx2[qq] = __fadd_rn(__fadd_rn(__fmul_rn(q0[qq], q0[qq]), __fmul_rn(q1[qq], q1[qq])),
                        __fmul_rn(q2[qq], q2[qq]));
#pragma unroll
    for (int k = 0; k < 8; ++k) { tv[qq][k] = -INFINITY; ti[qq][k] = 0x7fffffff; }
  }
  for (int c = 0; c < 4; ++c) {
    __syncthreads();
    for (int i = tid; i < 4096; i += 512) {
      int gi = c * 4096 + i;
      float a0 = ldany(xv, base0 + gi, f32);
      float a1 = ldany(xv, base1 + gi, f32);
      float a2 = ldany(xv, base2 + gi, f32);
      float xx = __fadd_rn(__fadd_rn(__fmul_rn(a0, a0), __fmul_rn(a1, a1)), __fmul_rn(a2, a2));
      s4[i] = make_float4(a0, a1, a2, xx);
    }
    __syncthreads();
    for (int t = 0; t < 128; ++t) {
      float4 v = s4[t * 32 + j];
      int ix = c * 4096 + t * 32 + j;       // increasing in-thread: ties correctly lose
#pragma unroll
      for (int qq = 0; qq < 2; ++qq) {
        float dot = __fadd_rn(__fadd_rn(__fmul_rn(v.x, q0[qq]), __fmul_rn(v.y, q1[qq])),
                              __fmul_rn(v.z, q2[qq]));
        float inner = __fmul_rn(-2.0f, dot);
        float d = __fsub_rn(__fsub_rn(-v.w, inner), xx2[qq]);
        if (d > tv[qq][7]) {
          float vv = d; int iix = ix;
#pragma unroll
          for (int k = 0; k < 8; ++k) {     // sorted insert (val desc, idx asc)
            bool sw = (vv > tv[qq][k]) || (vv == tv[qq][k] && iix < ti[qq][k]);
            float ov = tv[qq][k]; int oi = ti[qq][k];
            tv[qq][k] = sw ? vv : tv[qq][k]; ti[qq][k] = sw ? iix : ti[qq][k];
            vv = sw ? ov : vv;               iix = sw ? oi : iix;
          }
        }
      }
    }
  }
  // exact 8-round merge of the 32 lanes' sorted lists (val desc, idx asc)
#pragma unroll
  for (int qq = 0; qq < 2; ++qq) {
    int mywin = 0;
#pragma unroll
    for (int r = 0; r < 8; ++r) {
      float v = tv[qq][0]; int ix = ti[qq][0];
      for (int m = 1; m < 32; m <<= 1) {
        float ov = __shfl_xor(v, m, 32); int op = __shfl_xor(ix, m, 32);
        if (ov > v || (ov == v && op < ix)) { v = ov; ix = op; }
      }
      if (j == r) mywin = ix;                // lane r keeps rank r
      if (ti[qq][0] == ix) {                 // winner consumes its head (idx unique/thread)
#pragma unroll
        for (int k = 0; k < 7; ++k) { tv[qq][k] = tv[qq][k + 1]; ti[qq][k] = ti[qq][k + 1]; }
        tv[qq][7] = -INFINITY; ti[qq][7] = 0x7fffffff;
      }
    }
    if (j < 8) {
      int s = (sg0 + qq) & (S_ - 1);
      g_idxk[b * 32768 + j * 4096 + s] = mywin;  // rank-major (B,k,s) like ref
    }
  }
}

// ---------------- helper: gather + the two matvecs for one element ----------------
__device__ __forceinline__ void elem_vals(const void* xv, int xf32, int xbase,
                                          const int* fb, int n,
                                          const float* sWpos, const float* sbpos,
                                          const float* sWconv, const float* sbconv,
                                          float* val /*[64]*/) {
  int p = fb[n] & (P_ - 1);
  int p0 = fb[n & ~7] & (P_ - 1);           // j=0 slot of same group
  float xvv[4];
#pragma unroll
  for (int c = 0; c < 4; ++c) xvv[c] = ldany(xv, xbase + c * P_ + p, xf32);
  float pc[3];
#pragma unroll
  for (int c = 0; c < 3; ++c) pc[c] = ldany(xv, xbase + c * P_ + p0, xf32);
  float d0 = xvv[0] - pc[0], d1 = xvv[1] - pc[1], d2 = xvv[2] - pc[2];
  float sq = d0 * d0 + d1 * d1 + d2 * d2;
  float temp = (sq > 0.0f) ? sqrtf(sq) : 0.0f;
  float pe[10] = {xvv[0], xvv[1], xvv[2], pc[0], pc[1], pc[2], d0, d1, d2, temp};
#pragma unroll
  for (int o = 0; o < 32; ++o) {            // val[0..31] = conv branch
    float acc = sbconv[o];
#pragma unroll
    for (int c = 0; c < 4; ++c) acc = fmaf(sWconv[o * 4 + c], xvv[c], acc);
    val[o] = acc;
  }
#pragma unroll
  for (int o = 0; o < 32; ++o) {            // val[32..63] = pos branch
    float acc = sbpos[o];
#pragma unroll
    for (int c = 0; c < 10; ++c) acc = fmaf(sWpos[o * 10 + c], pe[c], acc);
    val[32 + o] = acc;
  }
}

// ---------------- BN partial sums ----------------
__global__ __launch_bounds__(256) void k_partial(const void* __restrict__ x,
                                                 const void* __restrict__ Wpos,
                                                 const void* __restrict__ bpos,
                                                 const void* __restrict__ Wconv,
                                                 const void* __restrict__ bconv) {
  __shared__ float sWpos[320], sbpos[32], sWconv[128], sbconv[32];
  __shared__ float sacc[4][128];
  int tid = threadIdx.x;
  int xf32 = g_f32x, wf32 = g_f32w;
  for (int i2 = tid; i2 < 320; i2 += 256) sWpos[i2] = ldany(Wpos, i2, wf32);
  if (tid < 128) sWconv[tid] = ldany(Wconv, tid, wf32);
  if (tid < 32) { sbpos[tid] = ldany(bpos, tid, wf32); sbconv[tid] = ldany(bconv, tid, wf32); }
  __syncthreads();
  int t = blockIdx.x * 256 + tid;          // < 65536
  int b = t >> 15, n = t & 32767;
  const int* fb = g_idxk + b * 32768;
  float val[64];
  elem_vals(x, xf32, b * C_ * P_, fb, n, sWpos, sbpos, sWconv, sbconv, val);
  int wid = tid >> 6, lane = tid & 63;
#pragma unroll
  for (int c = 0; c < 64; ++c) {
    float s = val[c], q = val[c] * val[c];
    for (int off = 32; off; off >>= 1) {
      s += __shfl_down(s, off);
      q += __shfl_down(q, off);
    }
    if (lane == 0) { sacc[wid][c * 2] = s; sacc[wid][c * 2 + 1] = q; }
  }
  __syncthreads();
  if (tid < 128) {
    g_partials[blockIdx.x * 128 + tid] =
        sacc[0][tid] + sacc[1][tid] + sacc[2][tid] + sacc[3][tid];
  }
}

// ---------------- finalize BN stats ----------------
__global__ void k_finalize(const void* __restrict__ g1, const void* __restrict__ be1,
                           const void* __restrict__ g2, const void* __restrict__ be2) {
  int ch = threadIdx.x;                    // blockDim = 64
  if (ch >= 64) return;
  int wf32 = g_f32w;
  float sum = 0.f, sq = 0.f;
  for (int blk = 0; blk < 256; ++blk) {
    sum += g_partials[blk * 128 + ch * 2];
    sq  += g_partials[blk * 128 + ch * 2 + 1];
  }
  float mean = sum * (1.0f / 65536.0f);
  float var = sq * (1.0f / 65536.0f) - mean * mean;
  int o = ch & 31;
  float g  = ldany(ch < 32 ? g1 : g2, o, wf32);
  float be = ldany(ch < 32 ? be1 : be2, o, wf32);
  float scale = g / sqrtf(var + 1e-5f);
  g_stats[ch * 2] = scale;
  g_stats[ch * 2 + 1] = be - mean * scale;
}

// ---------------- pass 2 : recompute + BN + attention + output ----------------
__global__ __launch_bounds__(256) void k_pass2(const void* __restrict__ x,
                                               const void* __restrict__ Wpos,
                                               const void* __restrict__ bpos,
                                               const void* __restrict__ Wconv,
                                               const void* __restrict__ bconv,
                                               const void* __restrict__ Wa1,
                                               const void* __restrict__ ba1,
                                               const void* __restrict__ Wa2,
                                               const void* __restrict__ ba2,
                                               const void* __restrict__ Wb1,
                                               const void* __restrict__ bb1,
                                               const void* __restrict__ Wb2,
                                               const void* __restrict__ bb2,
                                               void* __restrict__ out) {
  __shared__ float sWpos[320], sbpos[32], sWconv[128], sbconv[32];
  __shared__ float sWa1[2048], sba1[32], sWa2[32];
  __shared__ float sWb1[64 * 65];
  __shared__ float sbb1[64], sWb2[256], sbb2[64], sstats[128];
  __shared__ float sba2;
  int tid = threadIdx.x;
  int xf32 = g_f32x, wf32 = g_f32w;
  for (int i2 = tid; i2 < 320; i2 += 256) sWpos[i2] = ldany(Wpos, i2, wf32);
  if (tid < 128) sWconv[tid] = ldany(Wconv, tid, wf32);
  if (tid < 32) { sbpos[tid] = ldany(bpos, tid, wf32); sbconv[tid] = ldany(bconv, tid, wf32); }
  for (int i2 = tid; i2 < 2048; i2 += 256) sWa1[i2] = ldany(Wa1, i2, wf32);
  for (int i2 = tid; i2 < 4096; i2 += 256) sWb1[(i2 >> 6) * 65 + (i2 & 63)] = ldany(Wb1, i2, wf32);
  if (tid >= 32 && tid < 64) { sba1[tid - 32] = ldany(ba1, tid - 32, wf32); sWa2[tid - 32] = ldany(Wa2, tid - 32, wf32); }
  if (tid >= 64 && tid < 128) { sbb1[tid - 64] = ldany(bb1, tid - 64, wf32); sbb2[tid - 64] = ldany(bb2, tid - 64, wf32); }
  if (tid >= 128 && tid < 256) sstats[tid - 128] = g_stats[tid - 128];
  sWb2[tid] = ldany(Wb2, tid, wf32);
  if (tid == 0) sba2 = ldany(ba2, 0, wf32);
  __syncthreads();
  int g = blockIdx.x * 32 + (tid >> 3);     // group = (b,i)
  int j = tid & 7;
  int b = g >> 12, i = g & (S_ - 1);
  int n = i * 8 + j;
  const int* fb = g_idxk + b * 32768;
  int xbase = b * C_ * P_;
  float feat[64];
  elem_vals(x, xf32, xbase, fb, n, sWpos, sbpos, sWconv, sbconv, feat);
#pragma unroll
  for (int c = 0; c < 64; ++c) {
    float v = fmaf(feat[c], sstats[c * 2], sstats[c * 2 + 1]);
    feat[c] = (v >= 0.f) ? v : 0.2f * v;
  }
  float att = sba2;
  for (int h = 0; h < 32; ++h) {
    float acc = sba1[h];
#pragma unroll
    for (int c = 0; c < 64; ++c) acc = fmaf(sWa1[h * 64 + c], feat[c], acc);
    acc = (acc >= 0.f) ? acc : 0.2f * acc;
    att = fmaf(sWa2[h], acc, att);
  }
  float mxv = att;
  for (int mk = 1; mk < 8; mk <<= 1) mxv = fmaxf(mxv, __shfl_xor(mxv, mk, 8));
  float e = expf(att - mxv);
  float se = e;
  for (int mk = 1; mk < 8; mk <<= 1) se += __shfl_xor(se, mk, 8);
  float a = e / se;
#pragma unroll
  for (int c = 0; c < 64; ++c) {
    float w = feat[c] * a;
    w += __shfl_xor(w, 1, 8);
    w += __shfl_xor(w, 2, 8);
    w += __shfl_xor(w, 4, 8);
    feat[c] = w;
  }
  int p0 = fb[i * 8] & (P_ - 1);
  float xc0 = ldany(x, xbase + p0, xf32);
  float xc1 = ldany(x, xbase + P_ + p0, xf32);
  float xc2 = ldany(x, xbase + 2 * P_ + p0, xf32);
  float xc3 = ldany(x, xbase + 3 * P_ + p0, xf32);
  int obase = b * 69 * S_;
#pragma unroll
  for (int oc = 0; oc < 8; ++oc) {
    int o = j * 8 + oc;
    float acc = sbb1[o];
#pragma unroll
    for (int c = 0; c < 64; ++c) acc = fmaf(sWb1[o * 65 + c], feat[c], acc);
    float acc2 = sbb2[o];
    acc2 = fmaf(sWb2[o * 4 + 0], xc0, acc2);
    acc2 = fmaf(sWb2[o * 4 + 1], xc1, acc2);
    acc2 = fmaf(sWb2[o * 4 + 2], xc2, acc2);
    acc2 = fmaf(sWb2[o * 4 + 3], xc3, acc2);
    float r = acc + acc2;
    r = (r >= 0.f) ? r : 0.01f * r;
    int oi = obase + (5 + o) * S_ + i;
    if (xf32) ((float*)out)[oi] = r; else ((u16*)out)[oi] = f2bf(r);
  }
  if (j == 0) {                              // raw pass-through of x1[:, :5, :, 0]
#pragma unroll
    for (int c = 0; c < 5; ++c) {
      int oi = obase + c * S_ + i;
      if (xf32) ((float*)out)[oi] = ((const float*)x)[xbase + c * P_ + p0];
      else      ((u16*)out)[oi]   = ((const u16*)x)[xbase + c * P_ + p0];
    }
  }
}

extern "C" void kernel_launch(void* const* d_in, const int* in_sizes, int n_in,
                              void* d_out, int out_size, void* d_ws, size_t ws_size,
                              hipStream_t stream) {
  const void* x     = d_in[0];
  const void* Wpos  = d_in[1];
  const void* bpos  = d_in[2];
  const void* g2    = d_in[3];
  const void* be2   = d_in[4];
  const void* Wconv = d_in[5];
  const void* bconv = d_in[6];
  const void* g1    = d_in[7];
  const void* be1   = d_in[8];
  const void* Wa1   = d_in[9];
  const void* ba1   = d_in[10];
  const void* Wa2   = d_in[11];
  const void* ba2   = d_in[12];
  const void* Wb1   = d_in[13];
  const void* bb1   = d_in[14];
  const void* Wb2   = d_in[15];
  const void* bb2   = d_in[16];
  (void)d_ws; (void)ws_size; (void)in_sizes; (void)n_in;

  hipLaunchKernelGGL(k_detect, dim3(1), dim3(256), 0, stream,
                     x, Wpos, Wconv, Wa1, Wa2, Wb1, Wb2);
  hipLaunchKernelGGL(k_minmax, dim3(4), dim3(256), 0, stream, x);
  hipLaunchKernelGGL(k_knn1, dim3(256), dim3(512), 0, stream, x);
  hipLaunchKernelGGL(k_knn2, dim3(256), dim3(512), 0, stream, x);
  hipLaunchKernelGGL(k_partial, dim3(256), dim3(256), 0, stream, x,
                     Wpos, bpos, Wconv, bconv);
  hipLaunchKernelGGL(k_finalize, dim3(1), dim3(64), 0, stream,
                     g1, be1, g2, be2);
  hipLaunchKernelGGL(k_pass2, dim3(256), dim3(256), 0, stream, x,
                     Wpos, bpos, Wconv, bconv, Wa1, ba1, Wa2, ba2,
                     Wb1, bb1, Wb2, bb2, d_out);
}

// Round 8
// 366.608 us; speedup vs baseline: 2.0700x; 1.7056x over previous
//
#include <hip/hip_runtime.h>
#include <math.h>

#define B_ 2
#define P_ 16384
#define C_ 5
#define S_ 4096
#define KNN_ 8
#define L_ 64

typedef unsigned short u16;
typedef unsigned int u32;
typedef unsigned long long u64;

// ---- static scratch: fully rewritten every call before any read ----
__device__ int   g_f32x, g_f32w;               // dtype flags (1 = float32)
__device__ float g_mnmx[16];
__device__ int   g_idx0[B_ * S_];
__device__ int   g_idxk[B_ * KNN_ * S_];
__device__ float g_partials[256 * 128];
__device__ float g_stats[128];

__device__ __forceinline__ float bf2f(u16 u) {
  union { u32 i; float f; } c; c.i = ((u32)u) << 16; return c.f;
}
__device__ __forceinline__ u16 f2bf(float f) {
  union { float f; u32 i; } c; c.f = f;
  u32 r = c.i + 0x7fffu + ((c.i >> 16) & 1u);
  return (u16)(r >> 16);
}
// dtype-agnostic scalar load
__device__ __forceinline__ float ldany(const void* p, int i, int f32) {
  return f32 ? ((const float*)p)[i] : bf2f(((const u16*)p)[i]);
}

// ---- (d, idx) -> integer-valued double key; order == (d desc, idx asc); unique ----
__device__ __forceinline__ double packkey(float d, int idx) {
  u32 bits = __float_as_uint(d);
  u32 mask = (u32)(((int)bits) >> 31);
  u32 key = bits ^ (mask | 0x80000000u);     // monotone u32 map of f32 (d==0 always +0 here)
  u32 hi = key >> 18;                        // 46-bit pack: [key:32][16383-idx:14]
  u32 lo = (key << 14) | (u32)(16383 - idx);
  return fma((double)hi, 4294967296.0, (double)lo);   // exact (< 2^46)
}
__device__ __forceinline__ int keyidx(double w) {
  u32 hi = (u32)(w * (1.0 / 4294967296.0));  // exact truncation (w integer-valued)
  u32 lo = (u32)(w - (double)hi * 4294967296.0);
  return 16383 - (int)(lo & 16383u);
}
// branchless insert into sorted-desc 8-list (carry chain): 8 fmax + 8 fmin
__device__ __forceinline__ void ins8(double* t, double v) {
  double m = v;
#pragma unroll
  for (int k = 0; k < 8; ++k) {
    double mn = fmin(t[k], m);
    t[k] = fmax(t[k], m);
    m = mn;
  }
}

// ---------------- dtype detector ----------------
__device__ __forceinline__ int chk_bad(const void* p, int n, int tid) {
  int bad = 0;
  for (int i = tid; i < n; i += 256) {
    float f = bf2f(((const u16*)p)[i]);
    if (!(f == f) || fabsf(f) > 1024.0f) bad = 1;
  }
  return bad;
}
__global__ __launch_bounds__(256) void k_detect(const void* x, const void* wpos,
                                                const void* wconv, const void* wa1,
                                                const void* wa2, const void* wb1,
                                                const void* wb2) {
  __shared__ int sx, sw;
  int tid = threadIdx.x;
  if (tid == 0) { sx = 0; sw = 0; }
  __syncthreads();
  int bx = chk_bad(x, 1024, tid);
  int bw = chk_bad(wpos, 320, tid) | chk_bad(wconv, 128, tid) | chk_bad(wa1, 2048, tid)
         | chk_bad(wa2, 32, tid)   | chk_bad(wb1, 4096, tid)  | chk_bad(wb2, 256, tid);
  if (bx) atomicOr(&sx, 1);
  if (bw) atomicOr(&sw, 1);
  __syncthreads();
  if (tid == 0) { g_f32x = sx; g_f32w = sw; }
}

// ---------------- min/max over P for channels 0,1 ----------------
__global__ __launch_bounds__(256) void k_minmax(const void* __restrict__ x) {
  int f32 = g_f32x;
  int bc = blockIdx.x;            // 0..3 : b*2 + ch
  int b = bc >> 1, ch = bc & 1;
  int base = (b * C_ + ch) * P_;
  float mn = INFINITY, mx = -INFINITY;
  for (int p = threadIdx.x; p < P_; p += 256) {
    float v = ldany(x, base + p, f32);
    mn = fminf(mn, v); mx = fmaxf(mx, v);
  }
  for (int off = 32; off; off >>= 1) {
    mn = fminf(mn, __shfl_down(mn, off));
    mx = fmaxf(mx, __shfl_down(mx, off));
  }
  __shared__ float smn[4], smx[4];
  int wid = threadIdx.x >> 6;
  if ((threadIdx.x & 63) == 0) { smn[wid] = mn; smx[wid] = mx; }
  __syncthreads();
  if (threadIdx.x == 0) {
    for (int w = 1; w < 4; ++w) { mn = fminf(mn, smn[w]); mx = fmaxf(mx, smx[w]); }
    g_mnmx[bc * 2] = mn; g_mnmx[bc * 2 + 1] = mx;
  }
}

// ---------------- kNN #1 : nearest of 16384 2D points ----------------
// 1024 blocks x 256 thr; 8 queries/block; 64 lanes/query (one wave); 2 q/thread.
// Branchless top-1; contraction-free f32, np association order.
__global__ __launch_bounds__(256) void k_knn1(const void* __restrict__ xv) {
  __shared__ float4 s4[2048];               // (a0, a1, xx, 0) ; 32 KB
  const int f32 = g_f32x;
  int tid = threadIdx.x;
  int l = tid & 63, g = tid >> 6;           // g: 4 wave-groups
  int sg0 = blockIdx.x * 8 + g * 2;
  int b = sg0 >> 12;
  float mn0 = g_mnmx[(b * 2 + 0) * 2], mx0 = g_mnmx[(b * 2 + 0) * 2 + 1];
  float mn1 = g_mnmx[(b * 2 + 1) * 2], mx1 = g_mnmx[(b * 2 + 1) * 2 + 1];
  int base0 = b * C_ * P_, base1 = base0 + P_;
  float ps0[2], ps1[2], xx2[2], best[2]; int bestp[2];
#pragma unroll
  for (int qq = 0; qq < 2; ++qq) {
    int s = (sg0 + qq) & (S_ - 1);
    float mm0 = (float)(s & (L_ - 1)) * 0.015625f;
    float mm1 = (float)(s >> 6) * 0.015625f;
    ps0[qq] = __fadd_rn(__fmul_rn(mm0, __fsub_rn(mx0, mn0)), mn0);
    ps1[qq] = __fadd_rn(__fmul_rn(mm1, __fsub_rn(mx1, mn1)), mn1);
    xx2[qq] = __fadd_rn(__fmul_rn(ps0[qq], ps0[qq]), __fmul_rn(ps1[qq], ps1[qq]));
    best[qq] = -INFINITY; bestp[qq] = 0x7fffffff;
  }
  for (int c = 0; c < 8; ++c) {
    __syncthreads();
    for (int i = tid; i < 2048; i += 256) {
      int gi = c * 2048 + i;
      float a0 = ldany(xv, base0 + gi, f32);
      float a1 = ldany(xv, base1 + gi, f32);
      float xx = __fadd_rn(__fmul_rn(a0, a0), __fmul_rn(a1, a1));
      s4[i] = make_float4(a0, a1, xx, 0.0f);
    }
    __syncthreads();
    for (int t = 0; t < 32; ++t) {
      float4 v = s4[t * 64 + l];
      int ix = c * 2048 + t * 64 + l;       // strictly increasing in-thread
#pragma unroll
      for (int qq = 0; qq < 2; ++qq) {
        float dot = __fadd_rn(__fmul_rn(v.x, ps0[qq]), __fmul_rn(v.y, ps1[qq]));
        float inner = __fmul_rn(-2.0f, dot);
        float d = __fsub_rn(__fsub_rn(-v.z, inner), xx2[qq]);
        bool gt = d > best[qq];             // strict > keeps lowest idx on in-thread ties
        best[qq] = gt ? d : best[qq];
        bestp[qq] = gt ? ix : bestp[qq];
      }
    }
  }
#pragma unroll
  for (int qq = 0; qq < 2; ++qq) {
    float v = best[qq]; int ix = bestp[qq];
    for (int m = 1; m < 64; m <<= 1) {
      float ov = __shfl_xor(v, m, 64); int op = __shfl_xor(ix, m, 64);
      if (ov > v || (ov == v && op < ix)) { v = ov; ix = op; }
    }
    if (l == 0) g_idx0[sg0 + qq] = ix;
  }
}

// ---------------- kNN #2 : top-8 of 16384 3D points ----------------
// Same shape as knn1; branchless f64-packed-key 8-deep insert.
__global__ __launch_bounds__(256) void k_knn2(const void* __restrict__ xv) {
  __shared__ float4 s4[2048];               // (a0, a1, a2, xx) ; 32 KB
  const int f32 = g_f32x;
  int tid = threadIdx.x;
  int l = tid & 63, g = tid >> 6;
  int sg0 = blockIdx.x * 8 + g * 2;
  int b = sg0 >> 12;
  int base0 = b * C_ * P_, base1 = base0 + P_, base2 = base1 + P_;
  float q0[2], q1[2], q2[2], xx2[2];
  double t8[2][8];
#pragma unroll
  for (int qq = 0; qq < 2; ++qq) {
    int qi = g_idx0[sg0 + qq] & (P_ - 1);
    q0[qq] = ldany(xv, base0 + qi, f32);
    q1[qq] = ldany(xv, base1 + qi, f32);
    q2[qq] = ldany(xv, base2 + qi, f32);
    xx2[qq] = __fadd_rn(__fadd_rn(__fmul_rn(q0[qq], q0[qq]), __fmul_rn(q1[qq], q1[qq])),
                        __fmul_rn(q2[qq], q2[qq]));
#pragma unroll
    for (int k = 0; k < 8; ++k) t8[qq][k] = -1.0;   // below all keys (keys >= 0)
  }
  for (int c = 0; c < 8; ++c) {
    __syncthreads();
    for (int i = tid; i < 2048; i += 256) {
      int gi = c * 2048 + i;
      float a0 = ldany(xv, base0 + gi, f32);
      float a1 = ldany(xv, base1 + gi, f32);
      float a2 = ldany(xv, base2 + gi, f32);
      float xx = __fadd_rn(__fadd_rn(__fmul_rn(a0, a0), __fmul_rn(a1, a1)), __fmul_rn(a2, a2));
      s4[i] = make_float4(a0, a1, a2, xx);
    }
    __syncthreads();
    for (int t = 0; t < 32; ++t) {
      float4 v = s4[t * 64 + l];
      int ix = c * 2048 + t * 64 + l;
#pragma unroll
      for (int qq = 0; qq < 2; ++qq) {
        float dot = __fadd_rn(__fadd_rn(__fmul_rn(v.x, q0[qq]), __fmul_rn(v.y, q1[qq])),
                              __fmul_rn(v.z, q2[qq]));
        float inner = __fmul_rn(-2.0f, dot);
        float d = __fsub_rn(__fsub_rn(-v.w, inner), xx2[qq]);
        ins8(t8[qq], packkey(d, ix));       // branchless, exec every step
      }
    }
  }
  // 8 extraction rounds across the 64-lane wave (keys unique -> exact)
  double wk[2] = {0.0, 0.0};
#pragma unroll
  for (int qq = 0; qq < 2; ++qq) {
#pragma unroll
    for (int r = 0; r < 8; ++r) {
      double w = t8[qq][0];
      for (int m = 1; m < 64; m <<= 1) w = fmax(w, __shfl_xor(w, m, 64));
      if (l == r) wk[qq] = w;               // lane r keeps rank r
      bool cns = (t8[qq][0] == w);          // winner consumes its head
#pragma unroll
      for (int k = 0; k < 7; ++k) t8[qq][k] = cns ? t8[qq][k + 1] : t8[qq][k];
      t8[qq][7] = cns ? -1.0 : t8[qq][7];
    }
  }
  if (l < 8) {
#pragma unroll
    for (int qq = 0; qq < 2; ++qq) {
      int s = (sg0 + qq) & (S_ - 1);
      g_idxk[b * 32768 + l * 4096 + s] = keyidx(wk[qq]);   // rank-major (B,k,s)
    }
  }
}

// ---------------- helper: gather + the two matvecs for one element ----------------
__device__ __forceinline__ void elem_vals(const void* xv, int xf32, int xbase,
                                          const int* fb, int n,
                                          const float* sWpos, const float* sbpos,
                                          const float* sWconv, const float* sbconv,
                                          float* val /*[64]*/) {
  int p = fb[n] & (P_ - 1);
  int p0 = fb[n & ~7] & (P_ - 1);           // j=0 slot of same group
  float xvv[4];
#pragma unroll
  for (int c = 0; c < 4; ++c) xvv[c] = ldany(xv, xbase + c * P_ + p, xf32);
  float pc[3];
#pragma unroll
  for (int c = 0; c < 3; ++c) pc[c] = ldany(xv, xbase + c * P_ + p0, xf32);
  float d0 = xvv[0] - pc[0], d1 = xvv[1] - pc[1], d2 = xvv[2] - pc[2];
  float sq = d0 * d0 + d1 * d1 + d2 * d2;
  float temp = (sq > 0.0f) ? sqrtf(sq) : 0.0f;
  float pe[10] = {xvv[0], xvv[1], xvv[2], pc[0], pc[1], pc[2], d0, d1, d2, temp};
#pragma unroll
  for (int o = 0; o < 32; ++o) {            // val[0..31] = conv branch
    float acc = sbconv[o];
#pragma unroll
    for (int c = 0; c < 4; ++c) acc = fmaf(sWconv[o * 4 + c], xvv[c], acc);
    val[o] = acc;
  }
#pragma unroll
  for (int o = 0; o < 32; ++o) {            // val[32..63] = pos branch
    float acc = sbpos[o];
#pragma unroll
    for (int c = 0; c < 10; ++c) acc = fmaf(sWpos[o * 10 + c], pe[c], acc);
    val[32 + o] = acc;
  }
}

// ---------------- BN partial sums ----------------
__global__ __launch_bounds__(256) void k_partial(const void* __restrict__ x,
                                                 const void* __restrict__ Wpos,
                                                 const void* __restrict__ bpos,
                                                 const void* __restrict__ Wconv,
                                                 const void* __restrict__ bconv) {
  __shared__ float sWpos[320], sbpos[32], sWconv[128], sbconv[32];
  __shared__ float sacc[4][128];
  int tid = threadIdx.x;
  int xf32 = g_f32x, wf32 = g_f32w;
  for (int i2 = tid; i2 < 320; i2 += 256) sWpos[i2] = ldany(Wpos, i2, wf32);
  if (tid < 128) sWconv[tid] = ldany(Wconv, tid, wf32);
  if (tid < 32) { sbpos[tid] = ldany(bpos, tid, wf32); sbconv[tid] = ldany(bconv, tid, wf32); }
  __syncthreads();
  int t = blockIdx.x * 256 + tid;          // < 65536
  int b = t >> 15, n = t & 32767;
  const int* fb = g_idxk + b * 32768;
  float val[64];
  elem_vals(x, xf32, b * C_ * P_, fb, n, sWpos, sbpos, sWconv, sbconv, val);
  int wid = tid >> 6, lane = tid & 63;
#pragma unroll
  for (int c = 0; c < 64; ++c) {
    float s = val[c], q = val[c] * val[c];
    for (int off = 32; off; off >>= 1) {
      s += __shfl_down(s, off);
      q += __shfl_down(q, off);
    }
    if (lane == 0) { sacc[wid][c * 2] = s; sacc[wid][c * 2 + 1] = q; }
  }
  __syncthreads();
  if (tid < 128) {
    g_partials[blockIdx.x * 128 + tid] =
        sacc[0][tid] + sacc[1][tid] + sacc[2][tid] + sacc[3][tid];
  }
}

// ---------------- finalize BN stats ----------------
__global__ void k_finalize(const void* __restrict__ g1, const void* __restrict__ be1,
                           const void* __restrict__ g2, const void* __restrict__ be2) {
  int ch = threadIdx.x;                    // blockDim = 64
  if (ch >= 64) return;
  int wf32 = g_f32w;
  float sum = 0.f, sq = 0.f;
  for (int blk = 0; blk < 256; ++blk) {
    sum += g_partials[blk * 128 + ch * 2];
    sq  += g_partials[blk * 128 + ch * 2 + 1];
  }
  float mean = sum * (1.0f / 65536.0f);
  float var = sq * (1.0f / 65536.0f) - mean * mean;
  int o = ch & 31;
  float g  = ldany(ch < 32 ? g1 : g2, o, wf32);
  float be = ldany(ch < 32 ? be1 : be2, o, wf32);
  float scale = g / sqrtf(var + 1e-5f);
  g_stats[ch * 2] = scale;
  g_stats[ch * 2 + 1] = be - mean * scale;
}

// ---------------- pass 2 : recompute + BN + attention + output ----------------
__global__ __launch_bounds__(256) void k_pass2(const void* __restrict__ x,
                                               const void* __restrict__ Wpos,
                                               const void* __restrict__ bpos,
                                               const void* __restrict__ Wconv,
                                               const void* __restrict__ bconv,
                                               const void* __restrict__ Wa1,
                                               const void* __restrict__ ba1,
                                               const void* __restrict__ Wa2,
                                               const void* __restrict__ ba2,
                                               const void* __restrict__ Wb1,
                                               const void* __restrict__ bb1,
                                               const void* __restrict__ Wb2,
                                               const void* __restrict__ bb2,
                                               void* __restrict__ out) {
  __shared__ float sWpos[320], sbpos[32], sWconv[128], sbconv[32];
  __shared__ float sWa1[2048], sba1[32], sWa2[32];
  __shared__ float sWb1[64 * 65];
  __shared__ float sbb1[64], sWb2[256], sbb2[64], sstats[128];
  __shared__ float sba2;
  int tid = threadIdx.x;
  int xf32 = g_f32x, wf32 = g_f32w;
  for (int i2 = tid; i2 < 320; i2 += 256) sWpos[i2] = ldany(Wpos, i2, wf32);
  if (tid < 128) sWconv[tid] = ldany(Wconv, tid, wf32);
  if (tid < 32) { sbpos[tid] = ldany(bpos, tid, wf32); sbconv[tid] = ldany(bconv, tid, wf32); }
  for (int i2 = tid; i2 < 2048; i2 += 256) sWa1[i2] = ldany(Wa1, i2, wf32);
  for (int i2 = tid; i2 < 4096; i2 += 256) sWb1[(i2 >> 6) * 65 + (i2 & 63)] = ldany(Wb1, i2, wf32);
  if (tid >= 32 && tid < 64) { sba1[tid - 32] = ldany(ba1, tid - 32, wf32); sWa2[tid - 32] = ldany(Wa2, tid - 32, wf32); }
  if (tid >= 64 && tid < 128) { sbb1[tid - 64] = ldany(bb1, tid - 64, wf32); sbb2[tid - 64] = ldany(bb2, tid - 64, wf32); }
  if (tid >= 128 && tid < 256) sstats[tid - 128] = g_stats[tid - 128];
  sWb2[tid] = ldany(Wb2, tid, wf32);
  if (tid == 0) sba2 = ldany(ba2, 0, wf32);
  __syncthreads();
  int g = blockIdx.x * 32 + (tid >> 3);     // group = (b,i)
  int j = tid & 7;
  int b = g >> 12, i = g & (S_ - 1);
  int n = i * 8 + j;
  const int* fb = g_idxk + b * 32768;
  int xbase = b * C_ * P_;
  float feat[64];
  elem_vals(x, xf32, xbase, fb, n, sWpos, sbpos, sWconv, sbconv, feat);
#pragma unroll
  for (int c = 0; c < 64; ++c) {
    float v = fmaf(feat[c], sstats[c * 2], sstats[c * 2 + 1]);
    feat[c] = (v >= 0.f) ? v : 0.2f * v;
  }
  float att = sba2;
  for (int h = 0; h < 32; ++h) {
    float acc = sba1[h];
#pragma unroll
    for (int c = 0; c < 64; ++c) acc = fmaf(sWa1[h * 64 + c], feat[c], acc);
    acc = (acc >= 0.f) ? acc : 0.2f * acc;
    att = fmaf(sWa2[h], acc, att);
  }
  float mxv = att;
  for (int mk = 1; mk < 8; mk <<= 1) mxv = fmaxf(mxv, __shfl_xor(mxv, mk, 8));
  float e = expf(att - mxv);
  float se = e;
  for (int mk = 1; mk < 8; mk <<= 1) se += __shfl_xor(se, mk, 8);
  float a = e / se;
#pragma unroll
  for (int c = 0; c < 64; ++c) {
    float w = feat[c] * a;
    w += __shfl_xor(w, 1, 8);
    w += __shfl_xor(w, 2, 8);
    w += __shfl_xor(w, 4, 8);
    feat[c] = w;
  }
  int p0 = fb[i * 8] & (P_ - 1);
  float xc0 = ldany(x, xbase + p0, xf32);
  float xc1 = ldany(x, xbase + P_ + p0, xf32);
  float xc2 = ldany(x, xbase + 2 * P_ + p0, xf32);
  float xc3 = ldany(x, xbase + 3 * P_ + p0, xf32);
  int obase = b * 69 * S_;
#pragma unroll
  for (int oc = 0; oc < 8; ++oc) {
    int o = j * 8 + oc;
    float acc = sbb1[o];
#pragma unroll
    for (int c = 0; c < 64; ++c) acc = fmaf(sWb1[o * 65 + c], feat[c], acc);
    float acc2 = sbb2[o];
    acc2 = fmaf(sWb2[o * 4 + 0], xc0, acc2);
    acc2 = fmaf(sWb2[o * 4 + 1], xc1, acc2);
    acc2 = fmaf(sWb2[o * 4 + 2], xc2, acc2);
    acc2 = fmaf(sWb2[o * 4 + 3], xc3, acc2);
    float r = acc + acc2;
    r = (r >= 0.f) ? r : 0.01f * r;
    int oi = obase + (5 + o) * S_ + i;
    if (xf32) ((float*)out)[oi] = r; else ((u16*)out)[oi] = f2bf(r);
  }
  if (j == 0) {                              // raw pass-through of x1[:, :5, :, 0]
#pragma unroll
    for (int c = 0; c < 5; ++c) {
      int oi = obase + c * S_ + i;
      if (xf32) ((float*)out)[oi] = ((const float*)x)[xbase + c * P_ + p0];
      else      ((u16*)out)[oi]   = ((const u16*)x)[xbase + c * P_ + p0];
    }
  }
}

extern "C" void kernel_launch(void* const* d_in, const int* in_sizes, int n_in,
                              void* d_out, int out_size, void* d_ws, size_t ws_size,
                              hipStream_t stream) {
  const void* x     = d_in[0];
  const void* Wpos  = d_in[1];
  const void* bpos  = d_in[2];
  const void* g2    = d_in[3];
  const void* be2   = d_in[4];
  const void* Wconv = d_in[5];
  const void* bconv = d_in[6];
  const void* g1    = d_in[7];
  const void* be1   = d_in[8];
  const void* Wa1   = d_in[9];
  const void* ba1   = d_in[10];
  const void* Wa2   = d_in[11];
  const void* ba2   = d_in[12];
  const void* Wb1   = d_in[13];
  const void* bb1   = d_in[14];
  const void* Wb2   = d_in[15];
  const void* bb2   = d_in[16];
  (void)d_ws; (void)ws_size; (void)in_sizes; (void)n_in;

  hipLaunchKernelGGL(k_detect, dim3(1), dim3(256), 0, stream,
                     x, Wpos, Wconv, Wa1, Wa2, Wb1, Wb2);
  hipLaunchKernelGGL(k_minmax, dim3(4), dim3(256), 0, stream, x);
  hipLaunchKernelGGL(k_knn1, dim3(1024), dim3(256), 0, stream, x);
  hipLaunchKernelGGL(k_knn2, dim3(1024), dim3(256), 0, stream, x);
  hipLaunchKernelGGL(k_partial, dim3(256), dim3(256), 0, stream, x,
                     Wpos, bpos, Wconv, bconv);
  hipLaunchKernelGGL(k_finalize, dim3(1), dim3(64), 0, stream,
                     g1, be1, g2, be2);
  hipLaunchKernelGGL(k_pass2, dim3(256), dim3(256), 0, stream, x,
                     Wpos, bpos, Wconv, bconv, Wa1, ba1, Wa2, ba2,
                     Wb1, bb1, Wb2, bb2, d_out);
}

// Round 9
// 315.305 us; speedup vs baseline: 2.4068x; 1.1627x over previous
//
#include <hip/hip_runtime.h>
#include <math.h>

#define B_ 2
#define P_ 16384
#define C_ 5
#define S_ 4096
#define KNN_ 8
#define L_ 64

typedef unsigned short u16;
typedef unsigned int u32;

// ---- static scratch: fully rewritten every call before any read ----
__device__ int   g_f32x, g_f32w;               // dtype flags (1 = float32)
__device__ float g_mnmx[16];
__device__ int   g_idxk[B_ * KNN_ * S_];
__device__ float g_partials[256 * 128];
__device__ float g_stats[128];

__device__ __forceinline__ float bf2f(u16 u) {
  union { u32 i; float f; } c; c.i = ((u32)u) << 16; return c.f;
}
__device__ __forceinline__ u16 f2bf(float f) {
  union { float f; u32 i; } c; c.f = f;
  u32 r = c.i + 0x7fffu + ((c.i >> 16) & 1u);
  return (u16)(r >> 16);
}
// dtype-agnostic scalar load
__device__ __forceinline__ float ldany(const void* p, int i, int f32) {
  return f32 ? ((const float*)p)[i] : bf2f(((const u16*)p)[i]);
}

// ---- (d, idx) -> fixed-exponent positive double; order == (d desc, idx asc); unique ----
// f64 bits: sign 0, exp 0x3FF, mantissa = key32:[51:20] | (16383-idx):[19:6]
__device__ __forceinline__ double packkey(float d, int idx) {
  u32 bits = __float_as_uint(d);
  u32 key = bits ^ ((u32)(((int)bits) >> 31) | 0x80000000u);  // monotone u32 map of f32
  int hi = (int)(0x3FF00000u | (key >> 12));
  int lo = (int)((key << 20) | ((u32)(16383 - idx) << 6));
  return __hiloint2double(hi, lo);
}
__device__ __forceinline__ int keyidx(double w) {
  return 16383 - (int)(((u32)__double2loint(w) >> 6) & 16383u);
}
// branchless insert into sorted-desc 8-list (carry chain): 8 fmax + 8 fmin
__device__ __forceinline__ void ins8(double* t, double v) {
  double m = v;
#pragma unroll
  for (int k = 0; k < 8; ++k) {
    double mn = fmin(t[k], m);
    t[k] = fmax(t[k], m);
    m = mn;
  }
}

// ---------------- prep: dtype detect (block 0) + minmax (blocks 1..4) ----------------
__device__ __forceinline__ int chk_bad(const void* p, int n, int tid) {
  int bad = 0;
  for (int i = tid; i < n; i += 256) {
    float f = bf2f(((const u16*)p)[i]);
    if (!(f == f) || fabsf(f) > 1024.0f) bad = 1;
  }
  return bad;
}
__global__ __launch_bounds__(256) void k_prep(const void* x, const void* wpos,
                                              const void* wconv, const void* wa1,
                                              const void* wa2, const void* wb1,
                                              const void* wb2) {
  int tid = threadIdx.x;
  if (blockIdx.x == 0) {
    __shared__ int sx, sw;
    if (tid == 0) { sx = 0; sw = 0; }
    __syncthreads();
    int bx = chk_bad(x, 1024, tid);
    int bw = chk_bad(wpos, 320, tid) | chk_bad(wconv, 128, tid) | chk_bad(wa1, 2048, tid)
           | chk_bad(wa2, 32, tid)   | chk_bad(wb1, 4096, tid)  | chk_bad(wb2, 256, tid);
    if (bx) atomicOr(&sx, 1);
    if (bw) atomicOr(&sw, 1);
    __syncthreads();
    if (tid == 0) { g_f32x = sx; g_f32w = sw; }
    return;
  }
  // minmax for bc = blockIdx.x-1 ; inline x-dtype detection (same data as block 0's check)
  __shared__ int sbad;
  if (tid == 0) sbad = 0;
  __syncthreads();
  if (chk_bad(x, 1024, tid)) atomicOr(&sbad, 1);
  __syncthreads();
  int f32 = sbad;
  int bc = blockIdx.x - 1;        // 0..3 : b*2 + ch
  int b = bc >> 1, ch = bc & 1;
  int base = (b * C_ + ch) * P_;
  float mn = INFINITY, mx = -INFINITY;
  for (int p = tid; p < P_; p += 256) {
    float v = ldany(x, base + p, f32);
    mn = fminf(mn, v); mx = fmaxf(mx, v);
  }
  for (int off = 32; off; off >>= 1) {
    mn = fminf(mn, __shfl_down(mn, off));
    mx = fmaxf(mx, __shfl_down(mx, off));
  }
  __shared__ float smn[4], smx[4];
  int wid = tid >> 6;
  if ((tid & 63) == 0) { smn[wid] = mn; smx[wid] = mx; }
  __syncthreads();
  if (tid == 0) {
    for (int w = 1; w < 4; ++w) { mn = fminf(mn, smn[w]); mx = fmaxf(mx, smx[w]); }
    g_mnmx[bc * 2] = mn; g_mnmx[bc * 2 + 1] = mx;
  }
}

// ---------------- fused kNN : phase A top-1 (2D grid queries), phase B top-8 (3D) ----------------
// 1024 blocks x 256 thr; 8 queries/block; 64 lanes/query; 2 q/thread; 16 KB LDS chunks.
__global__ __launch_bounds__(256, 6) void k_knn(const void* __restrict__ xv) {
  __shared__ float4 s4[1024];               // 16 KB
  __shared__ int sidx[8];
  const int f32 = g_f32x;
  int tid = threadIdx.x;
  int l = tid & 63, g = tid >> 6;           // 4 wave-groups, 2 queries each
  int sg0 = blockIdx.x * 8 + g * 2;
  int b = sg0 >> 12;
  int base0 = b * C_ * P_, base1 = base0 + P_, base2 = base1 + P_;

  // ---- phase A: nearest candidate (2D) for the 2 grid queries ----
  float mn0 = g_mnmx[(b * 2 + 0) * 2], mx0 = g_mnmx[(b * 2 + 0) * 2 + 1];
  float mn1 = g_mnmx[(b * 2 + 1) * 2], mx1 = g_mnmx[(b * 2 + 1) * 2 + 1];
  float ps0[2], ps1[2], xx2[2], best[2]; int bestp[2];
#pragma unroll
  for (int qq = 0; qq < 2; ++qq) {
    int s = (sg0 + qq) & (S_ - 1);
    float mm0 = (float)(s & (L_ - 1)) * 0.015625f;
    float mm1 = (float)(s >> 6) * 0.015625f;
    ps0[qq] = __fadd_rn(__fmul_rn(mm0, __fsub_rn(mx0, mn0)), mn0);
    ps1[qq] = __fadd_rn(__fmul_rn(mm1, __fsub_rn(mx1, mn1)), mn1);
    xx2[qq] = __fadd_rn(__fmul_rn(ps0[qq], ps0[qq]), __fmul_rn(ps1[qq], ps1[qq]));
    best[qq] = -INFINITY; bestp[qq] = 0x7fffffff;
  }
  for (int c = 0; c < 16; ++c) {
    __syncthreads();
    for (int i = tid; i < 1024; i += 256) {
      int gi = c * 1024 + i;
      float a0 = ldany(xv, base0 + gi, f32);
      float a1 = ldany(xv, base1 + gi, f32);
      float xx = __fadd_rn(__fmul_rn(a0, a0), __fmul_rn(a1, a1));
      s4[i] = make_float4(a0, a1, xx, 0.0f);
    }
    __syncthreads();
    for (int t = 0; t < 16; ++t) {
      float4 v = s4[t * 64 + l];
      int ix = c * 1024 + t * 64 + l;       // strictly increasing in-thread
#pragma unroll
      for (int qq = 0; qq < 2; ++qq) {
        float dot = __fadd_rn(__fmul_rn(v.x, ps0[qq]), __fmul_rn(v.y, ps1[qq]));
        float inner = __fmul_rn(-2.0f, dot);
        float d = __fsub_rn(__fsub_rn(-v.z, inner), xx2[qq]);
        bool gt = d > best[qq];             // strict > keeps lowest idx on in-thread ties
        best[qq] = gt ? d : best[qq];
        bestp[qq] = gt ? ix : bestp[qq];
      }
    }
  }
#pragma unroll
  for (int qq = 0; qq < 2; ++qq) {
    float v = best[qq]; int ix = bestp[qq];
    for (int m = 1; m < 64; m <<= 1) {
      float ov = __shfl_xor(v, m, 64); int op = __shfl_xor(ix, m, 64);
      if (ov > v || (ov == v && op < ix)) { v = ov; ix = op; }
    }
    if (l == 0) sidx[g * 2 + qq] = ix;
  }
  __syncthreads();

  // ---- phase B: top-8 (3D) for the 2 sampled queries ----
  float q0[2], q1[2], q2[2], xx3q[2];
  double t8[2][8];
#pragma unroll
  for (int qq = 0; qq < 2; ++qq) {
    int qi = sidx[g * 2 + qq] & (P_ - 1);
    q0[qq] = ldany(xv, base0 + qi, f32);
    q1[qq] = ldany(xv, base1 + qi, f32);
    q2[qq] = ldany(xv, base2 + qi, f32);
    xx3q[qq] = __fadd_rn(__fadd_rn(__fmul_rn(q0[qq], q0[qq]), __fmul_rn(q1[qq], q1[qq])),
                         __fmul_rn(q2[qq], q2[qq]));
#pragma unroll
    for (int k = 0; k < 8; ++k) t8[qq][k] = -1.0;   // below all keys (keys >= 1.0)
  }
  for (int c = 0; c < 16; ++c) {
    __syncthreads();
    for (int i = tid; i < 1024; i += 256) {
      int gi = c * 1024 + i;
      float a0 = ldany(xv, base0 + gi, f32);
      float a1 = ldany(xv, base1 + gi, f32);
      float a2 = ldany(xv, base2 + gi, f32);
      float xx = __fadd_rn(__fadd_rn(__fmul_rn(a0, a0), __fmul_rn(a1, a1)), __fmul_rn(a2, a2));
      s4[i] = make_float4(a0, a1, a2, xx);
    }
    __syncthreads();
    for (int t = 0; t < 16; ++t) {
      float4 v = s4[t * 64 + l];
      int ix = c * 1024 + t * 64 + l;
#pragma unroll
      for (int qq = 0; qq < 2; ++qq) {
        float dot = __fadd_rn(__fadd_rn(__fmul_rn(v.x, q0[qq]), __fmul_rn(v.y, q1[qq])),
                              __fmul_rn(v.z, q2[qq]));
        float inner = __fmul_rn(-2.0f, dot);
        float d = __fsub_rn(__fsub_rn(-v.w, inner), xx3q[qq]);
        ins8(t8[qq], packkey(d, ix));       // branchless, exec every step
      }
    }
  }
  // 8 extraction rounds across the 64-lane wave (keys unique -> exact)
  double wk[2] = {0.0, 0.0};
#pragma unroll
  for (int qq = 0; qq < 2; ++qq) {
#pragma unroll
    for (int r = 0; r < 8; ++r) {
      double w = t8[qq][0];
      for (int m = 1; m < 64; m <<= 1) w = fmax(w, __shfl_xor(w, m, 64));
      if (l == r) wk[qq] = w;               // lane r keeps rank r
      bool cns = (t8[qq][0] == w);          // only the winner consumes its head
#pragma unroll
      for (int k = 0; k < 7; ++k) t8[qq][k] = cns ? t8[qq][k + 1] : t8[qq][k];
      t8[qq][7] = cns ? -1.0 : t8[qq][7];
    }
  }
  if (l < 8) {
#pragma unroll
    for (int qq = 0; qq < 2; ++qq) {
      int s = (sg0 + qq) & (S_ - 1);
      g_idxk[b * 32768 + l * 4096 + s] = keyidx(wk[qq]);   // rank-major (B,k,s)
    }
  }
}

// ---------------- helper: gather + the two matvecs for one element ----------------
__device__ __forceinline__ void elem_vals(const void* xv, int xf32, int xbase,
                                          const int* fb, int n,
                                          const float* sWpos, const float* sbpos,
                                          const float* sWconv, const float* sbconv,
                                          float* val /*[64]*/) {
  int p = fb[n] & (P_ - 1);
  int p0 = fb[n & ~7] & (P_ - 1);           // j=0 slot of same group
  float xvv[4];
#pragma unroll
  for (int c = 0; c < 4; ++c) xvv[c] = ldany(xv, xbase + c * P_ + p, xf32);
  float pc[3];
#pragma unroll
  for (int c = 0; c < 3; ++c) pc[c] = ldany(xv, xbase + c * P_ + p0, xf32);
  float d0 = xvv[0] - pc[0], d1 = xvv[1] - pc[1], d2 = xvv[2] - pc[2];
  float sq = d0 * d0 + d1 * d1 + d2 * d2;
  float temp = (sq > 0.0f) ? sqrtf(sq) : 0.0f;
  float pe[10] = {xvv[0], xvv[1], xvv[2], pc[0], pc[1], pc[2], d0, d1, d2, temp};
#pragma unroll
  for (int o = 0; o < 32; ++o) {            // val[0..31] = conv branch
    float acc = sbconv[o];
#pragma unroll
    for (int c = 0; c < 4; ++c) acc = fmaf(sWconv[o * 4 + c], xvv[c], acc);
    val[o] = acc;
  }
#pragma unroll
  for (int o = 0; o < 32; ++o) {            // val[32..63] = pos branch
    float acc = sbpos[o];
#pragma unroll
    for (int c = 0; c < 10; ++c) acc = fmaf(sWpos[o * 10 + c], pe[c], acc);
    val[32 + o] = acc;
  }
}

// ---------------- BN partial sums ----------------
__global__ __launch_bounds__(256) void k_partial(const void* __restrict__ x,
                                                 const void* __restrict__ Wpos,
                                                 const void* __restrict__ bpos,
                                                 const void* __restrict__ Wconv,
                                                 const void* __restrict__ bconv) {
  __shared__ float sWpos[320], sbpos[32], sWconv[128], sbconv[32];
  __shared__ float sacc[4][128];
  int tid = threadIdx.x;
  int xf32 = g_f32x, wf32 = g_f32w;
  for (int i2 = tid; i2 < 320; i2 += 256) sWpos[i2] = ldany(Wpos, i2, wf32);
  if (tid < 128) sWconv[tid] = ldany(Wconv, tid, wf32);
  if (tid < 32) { sbpos[tid] = ldany(bpos, tid, wf32); sbconv[tid] = ldany(bconv, tid, wf32); }
  __syncthreads();
  int t = blockIdx.x * 256 + tid;          // < 65536
  int b = t >> 15, n = t & 32767;
  const int* fb = g_idxk + b * 32768;
  float val[64];
  elem_vals(x, xf32, b * C_ * P_, fb, n, sWpos, sbpos, sWconv, sbconv, val);
  int wid = tid >> 6, lane = tid & 63;
#pragma unroll
  for (int c = 0; c < 64; ++c) {
    float s = val[c], q = val[c] * val[c];
    for (int off = 32; off; off >>= 1) {
      s += __shfl_down(s, off);
      q += __shfl_down(q, off);
    }
    if (lane == 0) { sacc[wid][c * 2] = s; sacc[wid][c * 2 + 1] = q; }
  }
  __syncthreads();
  if (tid < 128) {
    g_partials[blockIdx.x * 128 + tid] =
        sacc[0][tid] + sacc[1][tid] + sacc[2][tid] + sacc[3][tid];
  }
}

// ---------------- finalize BN stats ----------------
__global__ void k_finalize(const void* __restrict__ g1, const void* __restrict__ be1,
                           const void* __restrict__ g2, const void* __restrict__ be2) {
  int ch = threadIdx.x;                    // blockDim = 64
  if (ch >= 64) return;
  int wf32 = g_f32w;
  float sum = 0.f, sq = 0.f;
  for (int blk = 0; blk < 256; ++blk) {
    sum += g_partials[blk * 128 + ch * 2];
    sq  += g_partials[blk * 128 + ch * 2 + 1];
  }
  float mean = sum * (1.0f / 65536.0f);
  float var = sq * (1.0f / 65536.0f) - mean * mean;
  int o = ch & 31;
  float g  = ldany(ch < 32 ? g1 : g2, o, wf32);
  float be = ldany(ch < 32 ? be1 : be2, o, wf32);
  float scale = g / sqrtf(var + 1e-5f);
  g_stats[ch * 2] = scale;
  g_stats[ch * 2 + 1] = be - mean * scale;
}

// ---------------- pass 2 : recompute + BN + attention + output ----------------
__global__ __launch_bounds__(256) void k_pass2(const void* __restrict__ x,
                                               const void* __restrict__ Wpos,
                                               const void* __restrict__ bpos,
                                               const void* __restrict__ Wconv,
                                               const void* __restrict__ bconv,
                                               const void* __restrict__ Wa1,
                                               const void* __restrict__ ba1,
                                               const void* __restrict__ Wa2,
                                               const void* __restrict__ ba2,
                                               const void* __restrict__ Wb1,
                                               const void* __restrict__ bb1,
                                               const void* __restrict__ Wb2,
                                               const void* __restrict__ bb2,
                                               void* __restrict__ out) {
  __shared__ float sWpos[320], sbpos[32], sWconv[128], sbconv[32];
  __shared__ float sWa1[2048], sba1[32], sWa2[32];
  __shared__ float sWb1[64 * 65];
  __shared__ float sbb1[64], sWb2[256], sbb2[64], sstats[128];
  __shared__ float sba2;
  int tid = threadIdx.x;
  int xf32 = g_f32x, wf32 = g_f32w;
  for (int i2 = tid; i2 < 320; i2 += 256) sWpos[i2] = ldany(Wpos, i2, wf32);
  if (tid < 128) sWconv[tid] = ldany(Wconv, tid, wf32);
  if (tid < 32) { sbpos[tid] = ldany(bpos, tid, wf32); sbconv[tid] = ldany(bconv, tid, wf32); }
  for (int i2 = tid; i2 < 2048; i2 += 256) sWa1[i2] = ldany(Wa1, i2, wf32);
  for (int i2 = tid; i2 < 4096; i2 += 256) sWb1[(i2 >> 6) * 65 + (i2 & 63)] = ldany(Wb1, i2, wf32);
  if (tid >= 32 && tid < 64) { sba1[tid - 32] = ldany(ba1, tid - 32, wf32); sWa2[tid - 32] = ldany(Wa2, tid - 32, wf32); }
  if (tid >= 64 && tid < 128) { sbb1[tid - 64] = ldany(bb1, tid - 64, wf32); sbb2[tid - 64] = ldany(bb2, tid - 64, wf32); }
  if (tid >= 128 && tid < 256) sstats[tid - 128] = g_stats[tid - 128];
  sWb2[tid] = ldany(Wb2, tid, wf32);
  if (tid == 0) sba2 = ldany(ba2, 0, wf32);
  __syncthreads();
  int g = blockIdx.x * 32 + (tid >> 3);     // group = (b,i)
  int j = tid & 7;
  int b = g >> 12, i = g & (S_ - 1);
  int n = i * 8 + j;
  const int* fb = g_idxk + b * 32768;
  int xbase = b * C_ * P_;
  float feat[64];
  elem_vals(x, xf32, xbase, fb, n, sWpos, sbpos, sWconv, sbconv, feat);
#pragma unroll
  for (int c = 0; c < 64; ++c) {
    float v = fmaf(feat[c], sstats[c * 2], sstats[c * 2 + 1]);
    feat[c] = (v >= 0.f) ? v : 0.2f * v;
  }
  float att = sba2;
  for (int h = 0; h < 32; ++h) {
    float acc = sba1[h];
#pragma unroll
    for (int c = 0; c < 64; ++c) acc = fmaf(sWa1[h * 64 + c], feat[c], acc);
    acc = (acc >= 0.f) ? acc : 0.2f * acc;
    att = fmaf(sWa2[h], acc, att);
  }
  float mxv = att;
  for (int mk = 1; mk < 8; mk <<= 1) mxv = fmaxf(mxv, __shfl_xor(mxv, mk, 8));
  float e = expf(att - mxv);
  float se = e;
  for (int mk = 1; mk < 8; mk <<= 1) se += __shfl_xor(se, mk, 8);
  float a = e / se;
#pragma unroll
  for (int c = 0; c < 64; ++c) {
    float w = feat[c] * a;
    w += __shfl_xor(w, 1, 8);
    w += __shfl_xor(w, 2, 8);
    w += __shfl_xor(w, 4, 8);
    feat[c] = w;
  }
  int p0 = fb[i * 8] & (P_ - 1);
  float xc0 = ldany(x, xbase + p0, xf32);
  float xc1 = ldany(x, xbase + P_ + p0, xf32);
  float xc2 = ldany(x, xbase + 2 * P_ + p0, xf32);
  float xc3 = ldany(x, xbase + 3 * P_ + p0, xf32);
  int obase = b * 69 * S_;
#pragma unroll
  for (int oc = 0; oc < 8; ++oc) {
    int o = j * 8 + oc;
    float acc = sbb1[o];
#pragma unroll
    for (int c = 0; c < 64; ++c) acc = fmaf(sWb1[o * 65 + c], feat[c], acc);
    float acc2 = sbb2[o];
    acc2 = fmaf(sWb2[o * 4 + 0], xc0, acc2);
    acc2 = fmaf(sWb2[o * 4 + 1], xc1, acc2);
    acc2 = fmaf(sWb2[o * 4 + 2], xc2, acc2);
    acc2 = fmaf(sWb2[o * 4 + 3], xc3, acc2);
    float r = acc + acc2;
    r = (r >= 0.f) ? r : 0.01f * r;
    int oi = obase + (5 + o) * S_ + i;
    if (xf32) ((float*)out)[oi] = r; else ((u16*)out)[oi] = f2bf(r);
  }
  if (j == 0) {                              // raw pass-through of x1[:, :5, :, 0]
#pragma unroll
    for (int c = 0; c < 5; ++c) {
      int oi = obase + c * S_ + i;
      if (xf32) ((float*)out)[oi] = ((const float*)x)[xbase + c * P_ + p0];
      else      ((u16*)out)[oi]   = ((const u16*)x)[xbase + c * P_ + p0];
    }
  }
}

extern "C" void kernel_launch(void* const* d_in, const int* in_sizes, int n_in,
                              void* d_out, int out_size, void* d_ws, size_t ws_size,
                              hipStream_t stream) {
  const void* x     = d_in[0];
  const void* Wpos  = d_in[1];
  const void* bpos  = d_in[2];
  const void* g2    = d_in[3];
  const void* be2   = d_in[4];
  const void* Wconv = d_in[5];
  const void* bconv = d_in[6];
  const void* g1    = d_in[7];
  const void* be1   = d_in[8];
  const void* Wa1   = d_in[9];
  const void* ba1   = d_in[10];
  const void* Wa2   = d_in[11];
  const void* ba2   = d_in[12];
  const void* Wb1   = d_in[13];
  const void* bb1   = d_in[14];
  const void* Wb2   = d_in[15];
  const void* bb2   = d_in[16];
  (void)d_ws; (void)ws_size; (void)in_sizes; (void)n_in;

  hipLaunchKernelGGL(k_prep, dim3(5), dim3(256), 0, stream,
                     x, Wpos, Wconv, Wa1, Wa2, Wb1, Wb2);
  hipLaunchKernelGGL(k_knn, dim3(1024), dim3(256), 0, stream, x);
  hipLaunchKernelGGL(k_partial, dim3(256), dim3(256), 0, stream, x,
                     Wpos, bpos, Wconv, bconv);
  hipLaunchKernelGGL(k_finalize, dim3(1), dim3(64), 0, stream,
                     g1, be1, g2, be2);
  hipLaunchKernelGGL(k_pass2, dim3(256), dim3(256), 0, stream, x,
                     Wpos, bpos, Wconv, bconv, Wa1, ba1, Wa2, ba2,
                     Wb1, bb1, Wb2, bb2, d_out);
}

// Round 10
// 298.881 us; speedup vs baseline: 2.5391x; 1.0550x over previous
//
#include <hip/hip_runtime.h>
#include <math.h>

#define B_ 2
#define P_ 16384
#define C_ 5
#define S_ 4096
#define KNN_ 8
#define L_ 64

typedef unsigned short u16;
typedef unsigned int u32;

// ---- static scratch: fully rewritten every call before any read ----
__device__ int   g_idxk[B_ * KNN_ * S_];
__device__ float g_sums[128];                  // BN sum/sumsq, atomically accumulated

__device__ __forceinline__ float bf2f(u16 u) {
  union { u32 i; float f; } c; c.i = ((u32)u) << 16; return c.f;
}
__device__ __forceinline__ u16 f2bf(float f) {
  union { float f; u32 i; } c; c.f = f;
  u32 r = c.i + 0x7fffu + ((c.i >> 16) & 1u);
  return (u16)(r >> 16);
}
__device__ __forceinline__ float ldany(const void* p, int i, int f32) {
  return f32 ? ((const float*)p)[i] : bf2f(((const u16*)p)[i]);
}

// ---- (d, idx) -> fixed-exponent positive double; order == (d desc, idx asc); unique ----
__device__ __forceinline__ double packkey(float d, int idx) {
  u32 bits = __float_as_uint(d);
  u32 key = bits ^ ((u32)(((int)bits) >> 31) | 0x80000000u);  // monotone u32 map of f32
  int hi = (int)(0x3FF00000u | (key >> 12));
  int lo = (int)((key << 20) | ((u32)(16383 - idx) << 6));
  return __hiloint2double(hi, lo);
}
__device__ __forceinline__ int keyidx(double w) {
  return 16383 - (int)(((u32)__double2loint(w) >> 6) & 16383u);
}
__device__ __forceinline__ void cmpswap(double& a, double& b) {
  double hi = fmax(a, b), lo = fmin(a, b);
  a = hi; b = lo;
}
// acc: sorted desc top-8; k: 8 new keys (unordered). After: acc = sorted desc top-8 of union.
__device__ __forceinline__ void flush8(double* a, double* k) {
  // Batcher odd-even merge sort 8, descending (19 comparators)
  cmpswap(k[0], k[1]); cmpswap(k[2], k[3]); cmpswap(k[4], k[5]); cmpswap(k[6], k[7]);
  cmpswap(k[0], k[2]); cmpswap(k[1], k[3]); cmpswap(k[4], k[6]); cmpswap(k[5], k[7]);
  cmpswap(k[1], k[2]); cmpswap(k[5], k[6]);
  cmpswap(k[0], k[4]); cmpswap(k[1], k[5]); cmpswap(k[2], k[6]); cmpswap(k[3], k[7]);
  cmpswap(k[2], k[4]); cmpswap(k[3], k[5]);
  cmpswap(k[1], k[2]); cmpswap(k[3], k[4]); cmpswap(k[5], k[6]);
  // top-8 of two sorted-desc 8-lists: elementwise max against reverse (bitonic result)
  a[0] = fmax(a[0], k[7]); a[1] = fmax(a[1], k[6]);
  a[2] = fmax(a[2], k[5]); a[3] = fmax(a[3], k[4]);
  a[4] = fmax(a[4], k[3]); a[5] = fmax(a[5], k[2]);
  a[6] = fmax(a[6], k[1]); a[7] = fmax(a[7], k[0]);
  // bitonic merge -> sorted desc (12 comparators)
  cmpswap(a[0], a[4]); cmpswap(a[1], a[5]); cmpswap(a[2], a[6]); cmpswap(a[3], a[7]);
  cmpswap(a[0], a[2]); cmpswap(a[1], a[3]); cmpswap(a[4], a[6]); cmpswap(a[5], a[7]);
  cmpswap(a[0], a[1]); cmpswap(a[2], a[3]); cmpswap(a[4], a[5]); cmpswap(a[6], a[7]);
}

__device__ __forceinline__ int chk_bad(const void* p, int n, int tid) {
  int bad = 0;
  for (int i = tid; i < n; i += 256) {
    float f = bf2f(((const u16*)p)[i]);
    if (!(f == f) || fabsf(f) > 1024.0f) bad = 1;
  }
  return bad;
}

// ---------------- fused kNN : inline detect+minmax, phase A top-1 (2D), phase B top-8 (3D) ----------------
// 1024 blocks x 256 thr; 8 queries/block; 64 lanes/query; 2 q/thread; 16 KB LDS chunks.
__global__ __launch_bounds__(256, 4) void k_knn(const void* __restrict__ xv) {
  __shared__ float4 s4[1024];               // 16 KB
  __shared__ int sidx[8];
  __shared__ int sbad;
  __shared__ float sred[16];
  int tid = threadIdx.x;
  if (blockIdx.x == 0 && tid < 128) g_sums[tid] = 0.0f;   // zero BN accumulators
  int l = tid & 63, g = tid >> 6;           // 4 wave-groups, 2 queries each
  int sg0 = blockIdx.x * 8 + g * 2;
  int b = sg0 >> 12;
  int base0 = b * C_ * P_, base1 = base0 + P_, base2 = base1 + P_;

  // dtype detect (per block; same data/criterion every block -> uniform)
  if (tid == 0) sbad = 0;
  __syncthreads();
  if (chk_bad(xv, 1024, tid)) atomicOr(&sbad, 1);
  __syncthreads();
  const int f32 = sbad;

  // min/max of channels 0,1 for this block's b (exact; order-independent)
  float mn0 = INFINITY, mx0 = -INFINITY, mn1 = INFINITY, mx1 = -INFINITY;
  for (int p = tid; p < P_; p += 256) {
    float v0 = ldany(xv, base0 + p, f32);
    float v1 = ldany(xv, base1 + p, f32);
    mn0 = fminf(mn0, v0); mx0 = fmaxf(mx0, v0);
    mn1 = fminf(mn1, v1); mx1 = fmaxf(mx1, v1);
  }
  for (int off = 32; off; off >>= 1) {
    mn0 = fminf(mn0, __shfl_down(mn0, off)); mx0 = fmaxf(mx0, __shfl_down(mx0, off));
    mn1 = fminf(mn1, __shfl_down(mn1, off)); mx1 = fmaxf(mx1, __shfl_down(mx1, off));
  }
  if (l == 0) {
    sred[g * 4 + 0] = mn0; sred[g * 4 + 1] = mx0;
    sred[g * 4 + 2] = mn1; sred[g * 4 + 3] = mx1;
  }
  __syncthreads();
  mn0 = fminf(fminf(sred[0], sred[4]), fminf(sred[8], sred[12]));
  mx0 = fmaxf(fmaxf(sred[1], sred[5]), fmaxf(sred[9], sred[13]));
  mn1 = fminf(fminf(sred[2], sred[6]), fminf(sred[10], sred[14]));
  mx1 = fmaxf(fmaxf(sred[3], sred[7]), fmaxf(sred[11], sred[15]));

  // ---- phase A: nearest candidate (2D) for the 2 grid queries ----
  float ps0[2], ps1[2], xx2[2], best[2]; int bestp[2];
#pragma unroll
  for (int qq = 0; qq < 2; ++qq) {
    int s = (sg0 + qq) & (S_ - 1);
    float mm0 = (float)(s & (L_ - 1)) * 0.015625f;
    float mm1 = (float)(s >> 6) * 0.015625f;
    ps0[qq] = __fadd_rn(__fmul_rn(mm0, __fsub_rn(mx0, mn0)), mn0);
    ps1[qq] = __fadd_rn(__fmul_rn(mm1, __fsub_rn(mx1, mn1)), mn1);
    xx2[qq] = __fadd_rn(__fmul_rn(ps0[qq], ps0[qq]), __fmul_rn(ps1[qq], ps1[qq]));
    best[qq] = -INFINITY; bestp[qq] = 0x7fffffff;
  }
  for (int c = 0; c < 16; ++c) {
    __syncthreads();
    for (int i = tid; i < 1024; i += 256) {
      int gi = c * 1024 + i;
      float a0 = ldany(xv, base0 + gi, f32);
      float a1 = ldany(xv, base1 + gi, f32);
      float xx = __fadd_rn(__fmul_rn(a0, a0), __fmul_rn(a1, a1));
      s4[i] = make_float4(a0, a1, xx, 0.0f);
    }
    __syncthreads();
    for (int t = 0; t < 16; ++t) {
      float4 v = s4[t * 64 + l];
      int ix = c * 1024 + t * 64 + l;       // strictly increasing in-thread
#pragma unroll
      for (int qq = 0; qq < 2; ++qq) {
        float dot = __fadd_rn(__fmul_rn(v.x, ps0[qq]), __fmul_rn(v.y, ps1[qq]));
        float inner = __fmul_rn(-2.0f, dot);
        float d = __fsub_rn(__fsub_rn(-v.z, inner), xx2[qq]);
        bool gt = d > best[qq];             // strict > keeps lowest idx on in-thread ties
        best[qq] = gt ? d : best[qq];
        bestp[qq] = gt ? ix : bestp[qq];
      }
    }
  }
#pragma unroll
  for (int qq = 0; qq < 2; ++qq) {
    float v = best[qq]; int ix = bestp[qq];
    for (int m = 1; m < 64; m <<= 1) {
      float ov = __shfl_xor(v, m, 64); int op = __shfl_xor(ix, m, 64);
      if (ov > v || (ov == v && op < ix)) { v = ov; ix = op; }
    }
    if (l == 0) sidx[g * 2 + qq] = ix;
  }
  __syncthreads();

  // ---- phase B: top-8 (3D) for the 2 sampled queries ----
  float q0[2], q1[2], q2[2], xx3q[2];
  double acc[2][8], kb[2][8];
#pragma unroll
  for (int qq = 0; qq < 2; ++qq) {
    int qi = sidx[g * 2 + qq] & (P_ - 1);
    q0[qq] = ldany(xv, base0 + qi, f32);
    q1[qq] = ldany(xv, base1 + qi, f32);
    q2[qq] = ldany(xv, base2 + qi, f32);
    xx3q[qq] = __fadd_rn(__fadd_rn(__fmul_rn(q0[qq], q0[qq]), __fmul_rn(q1[qq], q1[qq])),
                         __fmul_rn(q2[qq], q2[qq]));
#pragma unroll
    for (int k = 0; k < 8; ++k) acc[qq][k] = -1.0;   // below all keys (keys in [1,2))
  }
  for (int c = 0; c < 16; ++c) {
    __syncthreads();
    for (int i = tid; i < 1024; i += 256) {
      int gi = c * 1024 + i;
      float a0 = ldany(xv, base0 + gi, f32);
      float a1 = ldany(xv, base1 + gi, f32);
      float a2 = ldany(xv, base2 + gi, f32);
      float xx = __fadd_rn(__fadd_rn(__fmul_rn(a0, a0), __fmul_rn(a1, a1)), __fmul_rn(a2, a2));
      s4[i] = make_float4(a0, a1, a2, xx);
    }
    __syncthreads();
#pragma unroll
    for (int t = 0; t < 16; ++t) {
      float4 v = s4[t * 64 + l];
      int ix = c * 1024 + t * 64 + l;
#pragma unroll
      for (int qq = 0; qq < 2; ++qq) {
        float dot = __fadd_rn(__fadd_rn(__fmul_rn(v.x, q0[qq]), __fmul_rn(v.y, q1[qq])),
                              __fmul_rn(v.z, q2[qq]));
        float inner = __fmul_rn(-2.0f, dot);
        float d = __fsub_rn(__fsub_rn(-v.w, inner), xx3q[qq]);
        kb[qq][t & 7] = packkey(d, ix);
      }
      if ((t & 7) == 7) {                   // batch flush: exact top-8 union
        flush8(acc[0], kb[0]);
        flush8(acc[1], kb[1]);
      }
    }
  }
  // 8 extraction rounds across the 64-lane wave (keys unique -> exact)
  double wk[2] = {0.0, 0.0};
#pragma unroll
  for (int qq = 0; qq < 2; ++qq) {
#pragma unroll
    for (int r = 0; r < 8; ++r) {
      double w = acc[qq][0];
      for (int m = 1; m < 64; m <<= 1) w = fmax(w, __shfl_xor(w, m, 64));
      if (l == r) wk[qq] = w;               // lane r keeps rank r
      bool cns = (acc[qq][0] == w);         // only the winner consumes its head
#pragma unroll
      for (int k = 0; k < 7; ++k) acc[qq][k] = cns ? acc[qq][k + 1] : acc[qq][k];
      acc[qq][7] = cns ? -1.0 : acc[qq][7];
    }
  }
  if (l < 8) {
#pragma unroll
    for (int qq = 0; qq < 2; ++qq) {
      int s = (sg0 + qq) & (S_ - 1);
      g_idxk[b * 32768 + l * 4096 + s] = keyidx(wk[qq]);   // rank-major (B,k,s)
    }
  }
}

// ---------------- helper: gather + the two matvecs for one element ----------------
__device__ __forceinline__ void elem_vals(const void* xv, int xf32, int xbase,
                                          const int* fb, int n,
                                          const float* sWpos, const float* sbpos,
                                          const float* sWconv, const float* sbconv,
                                          float* val /*[64]*/) {
  int p = fb[n] & (P_ - 1);
  int p0 = fb[n & ~7] & (P_ - 1);           // j=0 slot of same group
  float xvv[4];
#pragma unroll
  for (int c = 0; c < 4; ++c) xvv[c] = ldany(xv, xbase + c * P_ + p, xf32);
  float pc[3];
#pragma unroll
  for (int c = 0; c < 3; ++c) pc[c] = ldany(xv, xbase + c * P_ + p0, xf32);
  float d0 = xvv[0] - pc[0], d1 = xvv[1] - pc[1], d2 = xvv[2] - pc[2];
  float sq = d0 * d0 + d1 * d1 + d2 * d2;
  float temp = (sq > 0.0f) ? sqrtf(sq) : 0.0f;
  float pe[10] = {xvv[0], xvv[1], xvv[2], pc[0], pc[1], pc[2], d0, d1, d2, temp};
#pragma unroll
  for (int o = 0; o < 32; ++o) {            // val[0..31] = conv branch
    float acc = sbconv[o];
#pragma unroll
    for (int c = 0; c < 4; ++c) acc = fmaf(sWconv[o * 4 + c], xvv[c], acc);
    val[o] = acc;
  }
#pragma unroll
  for (int o = 0; o < 32; ++o) {            // val[32..63] = pos branch
    float acc = sbpos[o];
#pragma unroll
    for (int c = 0; c < 10; ++c) acc = fmaf(sWpos[o * 10 + c], pe[c], acc);
    val[32 + o] = acc;
  }
}

// ---------------- BN partial sums (atomic accumulate) ----------------
__global__ __launch_bounds__(256) void k_partial(const void* __restrict__ x,
                                                 const void* __restrict__ Wpos,
                                                 const void* __restrict__ bpos,
                                                 const void* __restrict__ Wconv,
                                                 const void* __restrict__ bconv) {
  __shared__ float sWpos[320], sbpos[32], sWconv[128], sbconv[32];
  __shared__ float sacc[4][128];
  __shared__ int sbx, sbw;
  int tid = threadIdx.x;
  if (tid == 0) { sbx = 0; sbw = 0; }
  __syncthreads();
  if (chk_bad(x, 1024, tid)) atomicOr(&sbx, 1);
  if (chk_bad(Wpos, 320, tid) | chk_bad(Wconv, 128, tid)) atomicOr(&sbw, 1);
  __syncthreads();
  int xf32 = sbx, wf32 = sbw;
  for (int i2 = tid; i2 < 320; i2 += 256) sWpos[i2] = ldany(Wpos, i2, wf32);
  if (tid < 128) sWconv[tid] = ldany(Wconv, tid, wf32);
  if (tid < 32) { sbpos[tid] = ldany(bpos, tid, wf32); sbconv[tid] = ldany(bconv, tid, wf32); }
  __syncthreads();
  int t = blockIdx.x * 256 + tid;          // < 65536
  int b = t >> 15, n = t & 32767;
  const int* fb = g_idxk + b * 32768;
  float val[64];
  elem_vals(x, xf32, b * C_ * P_, fb, n, sWpos, sbpos, sWconv, sbconv, val);
  int wid = tid >> 6, lane = tid & 63;
#pragma unroll
  for (int c = 0; c < 64; ++c) {
    float s = val[c], q = val[c] * val[c];
    for (int off = 32; off; off >>= 1) {
      s += __shfl_down(s, off);
      q += __shfl_down(q, off);
    }
    if (lane == 0) { sacc[wid][c * 2] = s; sacc[wid][c * 2 + 1] = q; }
  }
  __syncthreads();
  if (tid < 128) {
    float v = sacc[0][tid] + sacc[1][tid] + sacc[2][tid] + sacc[3][tid];
    atomicAdd(&g_sums[tid], v);
  }
}

// ---------------- pass 2 : inline BN stats + recompute + attention + output ----------------
__global__ __launch_bounds__(256) void k_pass2(const void* __restrict__ x,
                                               const void* __restrict__ Wpos,
                                               const void* __restrict__ bpos,
                                               const void* __restrict__ Wconv,
                                               const void* __restrict__ bconv,
                                               const void* __restrict__ g1,
                                               const void* __restrict__ be1,
                                               const void* __restrict__ g2,
                                               const void* __restrict__ be2,
                                               const void* __restrict__ Wa1,
                                               const void* __restrict__ ba1,
                                               const void* __restrict__ Wa2,
                                               const void* __restrict__ ba2,
                                               const void* __restrict__ Wb1,
                                               const void* __restrict__ bb1,
                                               const void* __restrict__ Wb2,
                                               const void* __restrict__ bb2,
                                               void* __restrict__ out) {
  __shared__ float sWpos[320], sbpos[32], sWconv[128], sbconv[32];
  __shared__ float sWa1[2048], sba1[32], sWa2[32];
  __shared__ float sWb1[64 * 65];
  __shared__ float sbb1[64], sWb2[256], sbb2[64], sstats[128];
  __shared__ float sba2;
  __shared__ int sbx, sbw;
  int tid = threadIdx.x;
  if (tid == 0) { sbx = 0; sbw = 0; }
  __syncthreads();
  if (chk_bad(x, 1024, tid)) atomicOr(&sbx, 1);
  if (chk_bad(Wa1, 2048, tid) | chk_bad(Wb1, 4096, tid)) atomicOr(&sbw, 1);
  __syncthreads();
  int xf32 = sbx, wf32 = sbw;
  for (int i2 = tid; i2 < 320; i2 += 256) sWpos[i2] = ldany(Wpos, i2, wf32);
  if (tid < 128) sWconv[tid] = ldany(Wconv, tid, wf32);
  if (tid < 32) { sbpos[tid] = ldany(bpos, tid, wf32); sbconv[tid] = ldany(bconv, tid, wf32); }
  for (int i2 = tid; i2 < 2048; i2 += 256) sWa1[i2] = ldany(Wa1, i2, wf32);
  for (int i2 = tid; i2 < 4096; i2 += 256) sWb1[(i2 >> 6) * 65 + (i2 & 63)] = ldany(Wb1, i2, wf32);
  if (tid >= 32 && tid < 64) { sba1[tid - 32] = ldany(ba1, tid - 32, wf32); sWa2[tid - 32] = ldany(Wa2, tid - 32, wf32); }
  if (tid >= 64 && tid < 128) { sbb1[tid - 64] = ldany(bb1, tid - 64, wf32); sbb2[tid - 64] = ldany(bb2, tid - 64, wf32); }
  sWb2[tid] = ldany(Wb2, tid, wf32);
  if (tid == 0) sba2 = ldany(ba2, 0, wf32);
  if (tid >= 128 && tid < 192) {            // BN stats from atomic sums
    int ch = tid - 128;
    float sum = g_sums[ch * 2], sq = g_sums[ch * 2 + 1];
    float mean = sum * (1.0f / 65536.0f);
    float var = sq * (1.0f / 65536.0f) - mean * mean;
    int o = ch & 31;
    float gg = ldany(ch < 32 ? g1 : g2, o, wf32);
    float be = ldany(ch < 32 ? be1 : be2, o, wf32);
    float scale = gg / sqrtf(var + 1e-5f);
    sstats[ch * 2] = scale;
    sstats[ch * 2 + 1] = be - mean * scale;
  }
  __syncthreads();
  int g = blockIdx.x * 32 + (tid >> 3);     // group = (b,i)
  int j = tid & 7;
  int b = g >> 12, i = g & (S_ - 1);
  int n = i * 8 + j;
  const int* fb = g_idxk + b * 32768;
  int xbase = b * C_ * P_;
  float feat[64];
  elem_vals(x, xf32, xbase, fb, n, sWpos, sbpos, sWconv, sbconv, feat);
#pragma unroll
  for (int c = 0; c < 64; ++c) {
    float v = fmaf(feat[c], sstats[c * 2], sstats[c * 2 + 1]);
    feat[c] = (v >= 0.f) ? v : 0.2f * v;
  }
  float att = sba2;
  for (int h = 0; h < 32; ++h) {
    float acc = sba1[h];
#pragma unroll
    for (int c = 0; c < 64; ++c) acc = fmaf(sWa1[h * 64 + c], feat[c], acc);
    acc = (acc >= 0.f) ? acc : 0.2f * acc;
    att = fmaf(sWa2[h], acc, att);
  }
  float mxv = att;
  for (int mk = 1; mk < 8; mk <<= 1) mxv = fmaxf(mxv, __shfl_xor(mxv, mk, 8));
  float e = expf(att - mxv);
  float se = e;
  for (int mk = 1; mk < 8; mk <<= 1) se += __shfl_xor(se, mk, 8);
  float a = e / se;
#pragma unroll
  for (int c = 0; c < 64; ++c) {
    float w = feat[c] * a;
    w += __shfl_xor(w, 1, 8);
    w += __shfl_xor(w, 2, 8);
    w += __shfl_xor(w, 4, 8);
    feat[c] = w;
  }
  int p0 = fb[i * 8] & (P_ - 1);
  float xc0 = ldany(x, xbase + p0, xf32);
  float xc1 = ldany(x, xbase + P_ + p0, xf32);
  float xc2 = ldany(x, xbase + 2 * P_ + p0, xf32);
  float xc3 = ldany(x, xbase + 3 * P_ + p0, xf32);
  int obase = b * 69 * S_;
#pragma unroll
  for (int oc = 0; oc < 8; ++oc) {
    int o = j * 8 + oc;
    float acc = sbb1[o];
#pragma unroll
    for (int c = 0; c < 64; ++c) acc = fmaf(sWb1[o * 65 + c], feat[c], acc);
    float acc2 = sbb2[o];
    acc2 = fmaf(sWb2[o * 4 + 0], xc0, acc2);
    acc2 = fmaf(sWb2[o * 4 + 1], xc1, acc2);
    acc2 = fmaf(sWb2[o * 4 + 2], xc2, acc2);
    acc2 = fmaf(sWb2[o * 4 + 3], xc3, acc2);
    float r = acc + acc2;
    r = (r >= 0.f) ? r : 0.01f * r;
    int oi = obase + (5 + o) * S_ + i;
    if (xf32) ((float*)out)[oi] = r; else ((u16*)out)[oi] = f2bf(r);
  }
  if (j == 0) {                              // raw pass-through of x1[:, :5, :, 0]
#pragma unroll
    for (int c = 0; c < 5; ++c) {
      int oi = obase + c * S_ + i;
      if (xf32) ((float*)out)[oi] = ((const float*)x)[xbase + c * P_ + p0];
      else      ((u16*)out)[oi]   = ((const u16*)x)[xbase + c * P_ + p0];
    }
  }
}

extern "C" void kernel_launch(void* const* d_in, const int* in_sizes, int n_in,
                              void* d_out, int out_size, void* d_ws, size_t ws_size,
                              hipStream_t stream) {
  const void* x     = d_in[0];
  const void* Wpos  = d_in[1];
  const void* bpos  = d_in[2];
  const void* g2    = d_in[3];
  const void* be2   = d_in[4];
  const void* Wconv = d_in[5];
  const void* bconv = d_in[6];
  const void* g1    = d_in[7];
  const void* be1   = d_in[8];
  const void* Wa1   = d_in[9];
  const void* ba1   = d_in[10];
  const void* Wa2   = d_in[11];
  const void* ba2   = d_in[12];
  const void* Wb1   = d_in[13];
  const void* bb1   = d_in[14];
  const void* Wb2   = d_in[15];
  const void* bb2   = d_in[16];
  (void)d_ws; (void)ws_size; (void)in_sizes; (void)n_in;

  hipLaunchKernelGGL(k_knn, dim3(1024), dim3(256), 0, stream, x);
  hipLaunchKernelGGL(k_partial, dim3(256), dim3(256), 0, stream, x,
                     Wpos, bpos, Wconv, bconv);
  hipLaunchKernelGGL(k_pass2, dim3(256), dim3(256), 0, stream, x,
                     Wpos, bpos, Wconv, bconv, g1, be1, g2, be2,
                     Wa1, ba1, Wa2, ba2, Wb1, bb1, Wb2, bb2, d_out);
}